// Round 7
// baseline (1962.000 us; speedup 1.0000x reference)
//
#include <hip/hip_runtime.h>

// ---------------------------------------------------------------------------
// FastSpeech-style encoder, round 6:
//  - GEMM: BK=64 (32 MFMA/barrier), incremental staging pointers (no div/mod),
//    K as template param, 8-group XOR swizzle.
//  - Attention: P-buffer aliased into K-tile LDS + npS removed -> 35KB LDS,
//    4 blocks/CU (was 3).
// B=32 T=1024 D=256 NH=2 dk=128 D_HID=1024 L=4, conv1 k9p4, conv2 k1.
// ---------------------------------------------------------------------------

#define B_ 32
#define T_ 1024
#define D_ 256
#define NH_ 2
#define DK_ 128
#define DH_ 1024
#define L_ 4
#define MROWS (B_ * T_)        // 32768
#define KCONV (D_ * 9)         // 2304
#define TPAD 1032              // 4 zero + 1024 + 4 zero rows per batch (Hpad)

typedef unsigned short u16;
typedef short bf16x8 __attribute__((ext_vector_type(8)));
typedef float f32x4 __attribute__((ext_vector_type(4)));
typedef u16 u16x8 __attribute__((ext_vector_type(8)));

__device__ __forceinline__ float bf2f(u16 h) {
    union { unsigned int u; float f; } a;
    a.u = ((unsigned int)h) << 16;
    return a.f;
}

__device__ __forceinline__ u16 f2bf(float f) {
    union { float f; unsigned int u; } a;
    a.f = f;
    unsigned int r = a.u + 0x7fffu + ((a.u >> 16) & 1u);  // RNE
    return (u16)(r >> 16);
}

__device__ __forceinline__ void glds16(const u16* g, u16* l) {
    __builtin_amdgcn_global_load_lds(
        (const __attribute__((address_space(1))) void*)g,
        (__attribute__((address_space(3))) void*)l, 16, 0, 0);
}

// --------------------------- dtype detection -------------------------------
__global__ void detect_kernel(const void* wemb_raw, int* flag) {
    __shared__ int cnt;
    if (threadIdx.x == 0) cnt = 0;
    __syncthreads();
    const u16* p = (const u16*)wemb_raw;
    if (p[256 + threadIdx.x] != 0) atomicAdd(&cnt, 1);
    __syncthreads();
    if (threadIdx.x == 0) *flag = (cnt >= 128) ? 1 : 0;   // 1 = bf16, 0 = fp32
}

__global__ void cvt_any_kernel(const void* __restrict__ src, u16* __restrict__ dst,
                               int n, const int* __restrict__ flag) {
    int i = blockIdx.x * 256 + threadIdx.x;
    if (i >= n) return;
    if (*flag) dst[i] = ((const u16*)src)[i];
    else       dst[i] = f2bf(((const float*)src)[i]);
}

// conv1 weights [l][oc][ic=256][kpos=9] -> [l][oc][kpos*256+ic] bf16
__global__ void w1_reorder2_kernel(const float* __restrict__ srcf,
                                   const u16* __restrict__ srch,
                                   u16* __restrict__ out, int n,
                                   const int* __restrict__ flag) {
    int idx = blockIdx.x * 256 + threadIdx.x;
    if (idx >= n) return;
    int l  = idx / (DH_ * KCONV);
    int r  = idx % (DH_ * KCONV);
    int oc = r / KCONV;
    int kk = r % KCONV;
    int kpos = kk >> 8;
    int ic   = kk & 255;
    size_t si = (size_t)l * DH_ * D_ * 9 + (oc * D_ + ic) * 9 + kpos;
    out[idx] = (*flag) ? srch[si] : f2bf(srcf[si]);
}

__global__ void sentinel_kernel(void* out, int out_size) {
    int i = blockIdx.x * 256 + threadIdx.x;
    if (i < out_size) ((u16*)out)[i] = 0x42F6;  // 123.0 bf16 — "ws too small"
}

// --------------------------- small utility kernels -------------------------

__global__ void embed_kernel(const int* __restrict__ seq, const int* __restrict__ pos,
                             const u16* __restrict__ wemb, const u16* __restrict__ pemb,
                             float* __restrict__ X, float* __restrict__ NP) {
    int row = blockIdx.x;
    int d   = threadIdx.x;
    int s = seq[row];
    int p = pos[row];
    X[(size_t)row * D_ + d] = bf2f(wemb[s * D_ + d]) + bf2f(pemb[p * D_ + d]);
    if (d == 0) NP[row] = (s != 0) ? 1.0f : 0.0f;
}

__global__ void zero_pad_kernel(u16* __restrict__ Hp, int nb) {
    int i = blockIdx.x * 256 + threadIdx.x;
    if (i >= nb * 8 * 256) return;
    int b = i / (8 * 256);
    int r = (i / 256) & 7;
    int d = i & 255;
    int row = (r < 4) ? r : (1024 + r);
    Hp[(size_t)(b * TPAD + row) * D_ + d] = 0;
}

// LN: 4 rows/block (1 wave/row); out -> Hpad layout.
__global__ __launch_bounds__(256)
void ln_kernel(const float* __restrict__ x, const u16* __restrict__ g,
               const u16* __restrict__ bta, u16* __restrict__ outp) {
    int wave = threadIdx.x >> 6, lane = threadIdx.x & 63;
    int row = blockIdx.x * 4 + wave;
    const float* xr = x + (size_t)row * D_;
    float4 v = *(const float4*)&xr[lane * 4];
    float s  = v.x + v.y + v.z + v.w;
    float s2 = v.x * v.x + v.y * v.y + v.z * v.z + v.w * v.w;
#pragma unroll
    for (int d = 1; d < 64; d <<= 1) {
        s  += __shfl_xor(s,  d, 64);
        s2 += __shfl_xor(s2, d, 64);
    }
    float m   = s * (1.0f / 256.0f);
    float var = s2 * (1.0f / 256.0f) - m * m;
    float rr  = rsqrtf(var + 1e-5f);
    size_t orow = (size_t)((row >> 10) * TPAD + 4 + (row & 1023)) * D_;
    float vv[4] = {v.x, v.y, v.z, v.w};
#pragma unroll
    for (int k = 0; k < 4; k++) {
        int d = lane * 4 + k;
        outp[orow + d] = f2bf((vv[k] - m) * rr * bf2f(g[d]) + bf2f(bta[d]));
    }
}

__global__ void out_kernel(const float* __restrict__ X, const float* __restrict__ NP,
                           void* __restrict__ out, int out_size,
                           const int* __restrict__ flag) {
    int i = blockIdx.x * 256 + threadIdx.x;
    if (i >= out_size) return;
    const int n1 = MROWS * D_;
    float v = (i < n1) ? X[i] : NP[i - n1];
    if (*flag) ((u16*)out)[i] = f2bf(v);
    else       ((float*)out)[i] = v;
}

// ------------------------------- MFMA GEMM ---------------------------------
// C[M,N] = A[M,K] @ W^T, W: [N][K] bf16 row-major. 128x128 tile, BK=64,
// 256 threads (2x2 waves of 64x64, each 4x4 MFMA tiles of 16x16x32, 2 k-subs).
// AMAP: 0 plain A[M][K]; 1 Hpad rows (K=256); 2 Hpad im2col (K=2304,
//       kpos-inner walk: pointer +256/iter, rollover +64-2048).
// EPI:  0 bf16 (+bias); 1 bf16 (+bias, relu); 2 fp32 (+bias, +resid, *mask).
// LDS: 8 col-groups of 8 u16 per 64-col row, group stored at g^(row&7).
template <int AMAP, int EPI, int K>
__global__ __launch_bounds__(256)
void gemm_mfma(const u16* __restrict__ A, const u16* __restrict__ W,
               const u16* __restrict__ bias, const float* __restrict__ resid,
               const float* __restrict__ mask, void* __restrict__ Cp,
               int M, int N) {
    __shared__ __align__(16) u16 As[128 * 64];
    __shared__ __align__(16) u16 Bs[128 * 64];
    const int tid  = threadIdx.x;
    const int wave = tid >> 6, lane = tid & 63;
    const int quad = lane >> 4, l15 = lane & 15;
    const int m0 = blockIdx.y * 128, n0 = blockIdx.x * 128;
    const int wm = (wave >> 1) * 64, wn = (wave & 1) * 64;
    const int srow = wave * 32;                  // 32 staged rows per wave
    const int row8 = lane >> 3;                  // 0..7 within 8-row group
    const int grp  = ((lane & 7) ^ row8) * 8;    // swizzled col offset (u16)
    f32x4 acc[4][4] = {};

    // per-thread global staging pointers (instr q adds q*8 rows)
    const u16* pa;
    {
        int m = m0 + srow + row8;
        if (AMAP == 0) pa = A + (size_t)m * K + grp;
        else {
            int hr = (m >> 10) * TPAD + (m & 1023) + (AMAP == 1 ? 4 : 0);
            pa = A + (size_t)hr * D_ + grp;
        }
    }
    const u16* pb = W + (size_t)(n0 + srow + row8) * K + grp;
    constexpr size_t rsA = (AMAP == 0) ? (size_t)K : (size_t)D_;
    constexpr size_t rsB = (size_t)K;

    u16* lda = &As[srow * 64];
    u16* ldb = &Bs[srow * 64];
    const int rg = (quad ^ (l15 & 7)) * 8;       // read col group (u16 offset)

    int kpos = 0;
    constexpr int nkt = K / 64;
    for (int t = 0; t < nkt; t++) {
#pragma unroll
        for (int q = 0; q < 4; q++) {
            glds16(pa + (size_t)q * 8 * rsA, lda + q * 8 * 64);
            glds16(pb + (size_t)q * 8 * rsB, ldb + q * 8 * 64);
        }
        if (AMAP == 2) {
            if (kpos == 8) { kpos = 0; pa += 64 - 8 * 256; pb += 64 - 8 * 256; }
            else           { kpos++;  pa += 256;           pb += 256; }
        } else { pa += 64; pb += 64; }
        __builtin_amdgcn_s_waitcnt(0);
        __syncthreads();
#pragma unroll
        for (int ks = 0; ks < 2; ks++) {
            bf16x8 af[4], bfr[4];
#pragma unroll
            for (int i = 0; i < 4; i++)
                af[i] = *(const bf16x8*)&As[(wm + i * 16 + l15) * 64 + (rg ^ (ks * 32))];
#pragma unroll
            for (int j = 0; j < 4; j++)
                bfr[j] = *(const bf16x8*)&Bs[(wn + j * 16 + l15) * 64 + (rg ^ (ks * 32))];
#pragma unroll
            for (int i = 0; i < 4; i++)
#pragma unroll
                for (int j = 0; j < 4; j++)
                    acc[i][j] = __builtin_amdgcn_mfma_f32_16x16x32_bf16(
                        af[i], bfr[j], acc[i][j], 0, 0, 0);
        }
        __syncthreads();
    }

    float bv[4];
#pragma unroll
    for (int j = 0; j < 4; j++) bv[j] = bf2f(bias[n0 + wn + j * 16 + l15]);
#pragma unroll
    for (int i = 0; i < 4; i++) {
#pragma unroll
        for (int r = 0; r < 4; r++) {
            int m = m0 + wm + i * 16 + quad * 4 + r;
            float mk = (EPI == 2) ? mask[m] : 1.0f;
#pragma unroll
            for (int j = 0; j < 4; j++) {
                int n = n0 + wn + j * 16 + l15;
                float v = acc[i][j][r] + bv[j];
                if (EPI == 1) v = fmaxf(v, 0.0f);
                if (EPI == 2) {
                    v = (v + resid[(size_t)m * N + n]) * mk;
                    ((float*)Cp)[(size_t)m * N + n] = v;
                } else {
                    ((u16*)Cp)[(size_t)m * N + n] = f2bf(v);
                }
            }
        }
    }
}

// --------------------------- flash MFMA attention --------------------------
// QKV [Mc][768] bf16 (q|k|v, head h at cols h*128). Block (qt,h,b), 256 thr,
// 64 q/block (16/wave), K-tiles of 64 keys, online softmax, O -> Hpad bf16.
// LDS 35KB: Ks 64x136 (P-buffer aliased into it after QK), Vt 128x72 swizzled.
__global__ __launch_bounds__(256)
void attn_mfma(const u16* __restrict__ QKV, const float* __restrict__ NPg,
               u16* __restrict__ Hp) {
    __shared__ __align__(16) u16 KsPs[64 * 136];   // Ks; aliased as Ps post-QK
    __shared__ __align__(16) u16 Vt[128 * 72];
    u16* Ks  = KsPs;
    const int tid  = threadIdx.x;
    const int wave = tid >> 6, lane = tid & 63;
    const int quad = lane >> 4, l15 = lane & 15;
    const int qt = blockIdx.x, h = blockIdx.y, b = blockIdx.z;
    const int t0 = qt * 64;
    const float scale = 0.08838834764831845f;  // 1/sqrt(128)
    u16* Psw = KsPs + wave * 16 * 72;

    bf16x8 q_a[4];
#pragma unroll
    for (int s = 0; s < 4; s++)
        q_a[s] = *(const bf16x8*)(QKV
            + (size_t)(b * 1024 + t0 + wave * 16 + l15) * 768
            + h * DK_ + s * 32 + quad * 8);

    float m_st[4], l_st[4];
    f32x4 oacc[8] = {};
#pragma unroll
    for (int r = 0; r < 4; r++) { m_st[r] = -1e30f; l_st[r] = 0.0f; }

    for (int kk = 0; kk < 16; kk++) {
        const int k0 = kk * 64;
        if (kk) __syncthreads();   // prev tile's PV reads (Ps alias, Vt) done
#pragma unroll
        for (int p = 0; p < 4; p++) {
            int s = tid + p * 256;
            int key = s >> 4, dk0 = (s & 15) * 8;
            size_t grow = (size_t)(b * 1024 + k0 + key) * 768 + h * DK_;
            *(u16x8*)&Ks[key * 136 + dk0] = *(const u16x8*)(QKV + grow + 256 + dk0);
            u16x8 vv = *(const u16x8*)(QKV + grow + 512 + dk0);
            int colb = key ^ ((s & 7) << 3);
#pragma unroll
            for (int e = 0; e < 8; e++) Vt[(dk0 + e) * 72 + colb] = vv[e];
        }
        __syncthreads();

        f32x4 s4[4];
#pragma unroll
        for (int nt = 0; nt < 4; nt++) {
            f32x4 c = {0.f, 0.f, 0.f, 0.f};
#pragma unroll
            for (int s = 0; s < 4; s++) {
                bf16x8 kb = *(const bf16x8*)&Ks[(nt * 16 + l15) * 136 + s * 32 + quad * 8];
                c = __builtin_amdgcn_mfma_f32_16x16x32_bf16(q_a[s], kb, c, 0, 0, 0);
            }
            s4[nt] = c;
        }
        __syncthreads();           // all QK reads of Ks done; Ks area -> Ps

#pragma unroll
        for (int nt = 0; nt < 4; nt++) {
            bool pad = (NPg[b * 1024 + k0 + nt * 16 + l15] == 0.0f);
#pragma unroll
            for (int r = 0; r < 4; r++)
                s4[nt][r] = pad ? -1e30f : s4[nt][r] * scale;
        }
        float alpha[4];
#pragma unroll
        for (int r = 0; r < 4; r++) {
            float v = fmaxf(fmaxf(s4[0][r], s4[1][r]), fmaxf(s4[2][r], s4[3][r]));
#pragma unroll
            for (int d = 1; d < 16; d <<= 1) v = fmaxf(v, __shfl_xor(v, d, 64));
            float mnew = fmaxf(m_st[r], v);
            alpha[r] = __expf(m_st[r] - mnew);
            m_st[r] = mnew;
            l_st[r] *= alpha[r];
        }
#pragma unroll
        for (int nt = 0; nt < 4; nt++)
#pragma unroll
            for (int r = 0; r < 4; r++) s4[nt][r] = __expf(s4[nt][r] - m_st[r]);
#pragma unroll
        for (int r = 0; r < 4; r++) {
            float v = s4[0][r] + s4[1][r] + s4[2][r] + s4[3][r];
#pragma unroll
            for (int d = 1; d < 16; d <<= 1) v += __shfl_xor(v, d, 64);
            l_st[r] += v;
        }
#pragma unroll
        for (int dt = 0; dt < 8; dt++)
#pragma unroll
            for (int r = 0; r < 4; r++) oacc[dt][r] *= alpha[r];
#pragma unroll
        for (int nt = 0; nt < 4; nt++)
#pragma unroll
            for (int r = 0; r < 4; r++)
                Psw[(quad * 4 + r) * 72 + nt * 16 + l15] = f2bf(s4[nt][r]);
#pragma unroll
        for (int ks = 0; ks < 2; ks++) {
            bf16x8 pa = *(const bf16x8*)&Psw[l15 * 72 + ks * 32 + quad * 8];
#pragma unroll
            for (int dt = 0; dt < 8; dt++) {
                int d = dt * 16 + l15;
                int swr = ((d >> 3) & 7) << 3;
                bf16x8 vb = *(const bf16x8*)&Vt[d * 72 + ((ks * 32 + quad * 8) ^ swr)];
                oacc[dt] = __builtin_amdgcn_mfma_f32_16x16x32_bf16(pa, vb, oacc[dt], 0, 0, 0);
            }
        }
    }

#pragma unroll
    for (int r = 0; r < 4; r++) {
        float inv = 1.0f / l_st[r];
        int t = t0 + wave * 16 + quad * 4 + r;
        size_t orow = (size_t)(b * TPAD + 4 + t) * D_ + h * DK_;
#pragma unroll
        for (int dt = 0; dt < 8; dt++)
            Hp[orow + dt * 16 + l15] = f2bf(oacc[dt][r] * inv);
    }
}

// ------------------------------- driver ------------------------------------

static inline int cdiv(int a, int b) { return (a + b - 1) / b; }

extern "C" void kernel_launch(void* const* d_in, const int* in_sizes, int n_in,
                              void* d_out, int out_size, void* d_ws, size_t ws_size,
                              hipStream_t stream) {
    const int* seq = (const int*)d_in[0];
    const int* pos = (const int*)d_in[1];
    (void)in_sizes; (void)n_in;

    int   cb = 8, w1L = 1;
    int*   FLAG; float* X; float* NP; u16* Hpad; u16* SCR; u16* W1R;
    u16 *WEMB, *PEMB, *QKVW, *QKVB, *FCW, *FCB, *G1c, *B1c, *C1B, *C2W, *C2B, *G2c, *B2c;

    unsigned char* wsb = (unsigned char*)d_ws;
    size_t off;
    auto build = [&](int cb_, int w1L_) -> size_t {
        off = 0;
        auto take = [&](size_t bytes) {
            unsigned char* p = wsb + off;
            off += (bytes + 255) & ~(size_t)255;
            return p;
        };
        FLAG = (int*)  take(4);
        X    = (float*)take((size_t)MROWS * D_ * 4);
        NP   = (float*)take((size_t)MROWS * 4);
        Hpad = (u16*)  take((size_t)cb_ * TPAD * D_ * 2);
        SCR  = (u16*)  take((size_t)cb_ * T_ * DH_ * 2);
        W1R  = (u16*)  take((size_t)w1L_ * DH_ * KCONV * 2);
        WEMB = (u16*)  take((size_t)300 * D_ * 2);
        PEMB = (u16*)  take((size_t)3001 * D_ * 2);
        QKVW = (u16*)  take((size_t)L_ * 3 * D_ * D_ * 2);
        QKVB = (u16*)  take((size_t)L_ * 3 * D_ * 2);
        FCW  = (u16*)  take((size_t)L_ * D_ * D_ * 2);
        FCB  = (u16*)  take((size_t)L_ * D_ * 2);
        G1c  = (u16*)  take((size_t)L_ * D_ * 2);
        B1c  = (u16*)  take((size_t)L_ * D_ * 2);
        C1B  = (u16*)  take((size_t)L_ * DH_ * 2);
        C2W  = (u16*)  take((size_t)L_ * D_ * DH_ * 2);
        C2B  = (u16*)  take((size_t)L_ * D_ * 2);
        G2c  = (u16*)  take((size_t)L_ * D_ * 2);
        B2c  = (u16*)  take((size_t)L_ * D_ * 2);
        return off;
    };
    if      (build(32, L_) <= ws_size) { cb = 32; w1L = L_; }
    else if (build(8,  L_) <= ws_size) { cb = 8;  w1L = L_; }
    else if (build(8,  1)  <= ws_size) { cb = 8;  w1L = 1;  }
    else {
        sentinel_kernel<<<cdiv(out_size, 256), 256, 0, stream>>>(d_out, out_size);
        return;
    }
    const int nch = B_ / cb;
    const int Mc  = cb * T_;

    detect_kernel<<<1, 256, 0, stream>>>(d_in[2], FLAG);
    auto cvt = [&](const void* src, u16* dst, int n) {
        cvt_any_kernel<<<cdiv(n, 256), 256, 0, stream>>>(src, dst, n, FLAG);
    };
    cvt(d_in[2],  WEMB, 300 * D_);
    cvt(d_in[3],  PEMB, 3001 * D_);
    cvt(d_in[4],  QKVW, L_ * 3 * D_ * D_);
    cvt(d_in[5],  QKVB, L_ * 3 * D_);
    cvt(d_in[6],  FCW,  L_ * D_ * D_);
    cvt(d_in[7],  FCB,  L_ * D_);
    cvt(d_in[8],  G1c,  L_ * D_);
    cvt(d_in[9],  B1c,  L_ * D_);
    cvt(d_in[11], C1B,  L_ * DH_);
    cvt(d_in[12], C2W,  L_ * D_ * DH_);
    cvt(d_in[13], C2B,  L_ * D_);
    cvt(d_in[14], G2c,  L_ * D_);
    cvt(d_in[15], B2c,  L_ * D_);
    if (w1L == L_) {
        int n = L_ * DH_ * KCONV;
        w1_reorder2_kernel<<<cdiv(n, 256), 256, 0, stream>>>(
            (const float*)d_in[10], (const u16*)d_in[10], W1R, n, FLAG);
    }

    embed_kernel<<<MROWS, 256, 0, stream>>>(seq, pos, WEMB, PEMB, X, NP);
    zero_pad_kernel<<<cb * 8, 256, 0, stream>>>(Hpad, cb);

    for (int l = 0; l < L_; l++) {
        for (int c = 0; c < nch; c++) {
            const size_t ro = (size_t)c * Mc;
            ln_kernel<<<Mc / 4, 256, 0, stream>>>(
                X + ro * D_, G1c + l * D_, B1c + l * D_, Hpad);
            gemm_mfma<1, 0, 256><<<dim3(6, Mc / 128), 256, 0, stream>>>(
                Hpad, QKVW + (size_t)l * 3 * D_ * D_, QKVB + l * 3 * D_,
                nullptr, nullptr, SCR, Mc, 3 * D_);
            attn_mfma<<<dim3(16, NH_, cb), 256, 0, stream>>>(
                SCR, NP + ro, Hpad);
            gemm_mfma<1, 2, 256><<<dim3(2, Mc / 128), 256, 0, stream>>>(
                Hpad, FCW + (size_t)l * D_ * D_, FCB + l * D_,
                X + ro * D_, NP + ro, X + ro * D_, Mc, D_);
        }
        const u16* w1p = W1R + (w1L == L_ ? (size_t)l * DH_ * KCONV : 0);
        if (w1L != L_) {
            int n = DH_ * KCONV;
            w1_reorder2_kernel<<<cdiv(n, 256), 256, 0, stream>>>(
                (const float*)d_in[10] + (size_t)l * DH_ * D_ * 9,
                (const u16*)d_in[10] + (size_t)l * DH_ * D_ * 9,
                W1R, n, FLAG);
        }
        for (int c = 0; c < nch; c++) {
            const size_t ro = (size_t)c * Mc;
            ln_kernel<<<Mc / 4, 256, 0, stream>>>(
                X + ro * D_, G2c + l * D_, B2c + l * D_, Hpad);
            gemm_mfma<2, 1, 2304><<<dim3(8, Mc / 128), 256, 0, stream>>>(
                Hpad, w1p, C1B + l * DH_,
                nullptr, nullptr, SCR, Mc, DH_);
            gemm_mfma<0, 2, 1024><<<dim3(2, Mc / 128), 256, 0, stream>>>(
                SCR, C2W + (size_t)l * D_ * DH_, C2B + l * D_,
                X + ro * D_, NP + ro, X + ro * D_, Mc, D_);
        }
    }

    out_kernel<<<cdiv(out_size, 256), 256, 0, stream>>>(X, NP, d_out, out_size, FLAG);
}

// Round 8
// 1858.046 us; speedup vs baseline: 1.0559x; 1.0559x over previous
//
#include <hip/hip_runtime.h>

// ---------------------------------------------------------------------------
// FastSpeech-style encoder, round 7:
//  - Attention: XCD-locality grid (hb fastest -> all qt-blocks of one
//    (head,batch) share an XCD L2); npS prefetch restored. Round-6 regression
//    diagnosed as L2 thrash (FETCH 35->140MB) from full-residency streaming.
//  - GEMMs: keep round-6 BK=64 structure (conv1 improved).
// B=32 T=1024 D=256 NH=2 dk=128 D_HID=1024 L=4, conv1 k9p4, conv2 k1.
// ---------------------------------------------------------------------------

#define B_ 32
#define T_ 1024
#define D_ 256
#define NH_ 2
#define DK_ 128
#define DH_ 1024
#define L_ 4
#define MROWS (B_ * T_)        // 32768
#define KCONV (D_ * 9)         // 2304
#define TPAD 1032              // 4 zero + 1024 + 4 zero rows per batch (Hpad)

typedef unsigned short u16;
typedef short bf16x8 __attribute__((ext_vector_type(8)));
typedef float f32x4 __attribute__((ext_vector_type(4)));
typedef u16 u16x8 __attribute__((ext_vector_type(8)));

__device__ __forceinline__ float bf2f(u16 h) {
    union { unsigned int u; float f; } a;
    a.u = ((unsigned int)h) << 16;
    return a.f;
}

__device__ __forceinline__ u16 f2bf(float f) {
    union { float f; unsigned int u; } a;
    a.f = f;
    unsigned int r = a.u + 0x7fffu + ((a.u >> 16) & 1u);  // RNE
    return (u16)(r >> 16);
}

__device__ __forceinline__ void glds16(const u16* g, u16* l) {
    __builtin_amdgcn_global_load_lds(
        (const __attribute__((address_space(1))) void*)g,
        (__attribute__((address_space(3))) void*)l, 16, 0, 0);
}

// --------------------------- dtype detection -------------------------------
__global__ void detect_kernel(const void* wemb_raw, int* flag) {
    __shared__ int cnt;
    if (threadIdx.x == 0) cnt = 0;
    __syncthreads();
    const u16* p = (const u16*)wemb_raw;
    if (p[256 + threadIdx.x] != 0) atomicAdd(&cnt, 1);
    __syncthreads();
    if (threadIdx.x == 0) *flag = (cnt >= 128) ? 1 : 0;   // 1 = bf16, 0 = fp32
}

__global__ void cvt_any_kernel(const void* __restrict__ src, u16* __restrict__ dst,
                               int n, const int* __restrict__ flag) {
    int i = blockIdx.x * 256 + threadIdx.x;
    if (i >= n) return;
    if (*flag) dst[i] = ((const u16*)src)[i];
    else       dst[i] = f2bf(((const float*)src)[i]);
}

// conv1 weights [l][oc][ic=256][kpos=9] -> [l][oc][kpos*256+ic] bf16
__global__ void w1_reorder2_kernel(const float* __restrict__ srcf,
                                   const u16* __restrict__ srch,
                                   u16* __restrict__ out, int n,
                                   const int* __restrict__ flag) {
    int idx = blockIdx.x * 256 + threadIdx.x;
    if (idx >= n) return;
    int l  = idx / (DH_ * KCONV);
    int r  = idx % (DH_ * KCONV);
    int oc = r / KCONV;
    int kk = r % KCONV;
    int kpos = kk >> 8;
    int ic   = kk & 255;
    size_t si = (size_t)l * DH_ * D_ * 9 + (oc * D_ + ic) * 9 + kpos;
    out[idx] = (*flag) ? srch[si] : f2bf(srcf[si]);
}

__global__ void sentinel_kernel(void* out, int out_size) {
    int i = blockIdx.x * 256 + threadIdx.x;
    if (i < out_size) ((u16*)out)[i] = 0x42F6;  // 123.0 bf16 — "ws too small"
}

// --------------------------- small utility kernels -------------------------

__global__ void embed_kernel(const int* __restrict__ seq, const int* __restrict__ pos,
                             const u16* __restrict__ wemb, const u16* __restrict__ pemb,
                             float* __restrict__ X, float* __restrict__ NP) {
    int row = blockIdx.x;
    int d   = threadIdx.x;
    int s = seq[row];
    int p = pos[row];
    X[(size_t)row * D_ + d] = bf2f(wemb[s * D_ + d]) + bf2f(pemb[p * D_ + d]);
    if (d == 0) NP[row] = (s != 0) ? 1.0f : 0.0f;
}

__global__ void zero_pad_kernel(u16* __restrict__ Hp, int nb) {
    int i = blockIdx.x * 256 + threadIdx.x;
    if (i >= nb * 8 * 256) return;
    int b = i / (8 * 256);
    int r = (i / 256) & 7;
    int d = i & 255;
    int row = (r < 4) ? r : (1024 + r);
    Hp[(size_t)(b * TPAD + row) * D_ + d] = 0;
}

// LN: 4 rows/block (1 wave/row); out -> Hpad layout.
__global__ __launch_bounds__(256)
void ln_kernel(const float* __restrict__ x, const u16* __restrict__ g,
               const u16* __restrict__ bta, u16* __restrict__ outp) {
    int wave = threadIdx.x >> 6, lane = threadIdx.x & 63;
    int row = blockIdx.x * 4 + wave;
    const float* xr = x + (size_t)row * D_;
    float4 v = *(const float4*)&xr[lane * 4];
    float s  = v.x + v.y + v.z + v.w;
    float s2 = v.x * v.x + v.y * v.y + v.z * v.z + v.w * v.w;
#pragma unroll
    for (int d = 1; d < 64; d <<= 1) {
        s  += __shfl_xor(s,  d, 64);
        s2 += __shfl_xor(s2, d, 64);
    }
    float m   = s * (1.0f / 256.0f);
    float var = s2 * (1.0f / 256.0f) - m * m;
    float rr  = rsqrtf(var + 1e-5f);
    size_t orow = (size_t)((row >> 10) * TPAD + 4 + (row & 1023)) * D_;
    float vv[4] = {v.x, v.y, v.z, v.w};
#pragma unroll
    for (int k = 0; k < 4; k++) {
        int d = lane * 4 + k;
        outp[orow + d] = f2bf((vv[k] - m) * rr * bf2f(g[d]) + bf2f(bta[d]));
    }
}

__global__ void out_kernel(const float* __restrict__ X, const float* __restrict__ NP,
                           void* __restrict__ out, int out_size,
                           const int* __restrict__ flag) {
    int i = blockIdx.x * 256 + threadIdx.x;
    if (i >= out_size) return;
    const int n1 = MROWS * D_;
    float v = (i < n1) ? X[i] : NP[i - n1];
    if (*flag) ((u16*)out)[i] = f2bf(v);
    else       ((float*)out)[i] = v;
}

// ------------------------------- MFMA GEMM ---------------------------------
// C[M,N] = A[M,K] @ W^T, W: [N][K] bf16 row-major. 128x128 tile, BK=64,
// 256 threads (2x2 waves of 64x64, each 4x4 MFMA tiles of 16x16x32, 2 k-subs).
// AMAP: 0 plain A[M][K]; 1 Hpad rows (K=256); 2 Hpad im2col (K=2304,
//       kpos-inner walk: pointer +256/iter, rollover +64-2048).
// EPI:  0 bf16 (+bias); 1 bf16 (+bias, relu); 2 fp32 (+bias, +resid, *mask).
template <int AMAP, int EPI, int K>
__global__ __launch_bounds__(256)
void gemm_mfma(const u16* __restrict__ A, const u16* __restrict__ W,
               const u16* __restrict__ bias, const float* __restrict__ resid,
               const float* __restrict__ mask, void* __restrict__ Cp,
               int M, int N) {
    __shared__ __align__(16) u16 As[128 * 64];
    __shared__ __align__(16) u16 Bs[128 * 64];
    const int tid  = threadIdx.x;
    const int wave = tid >> 6, lane = tid & 63;
    const int quad = lane >> 4, l15 = lane & 15;
    const int m0 = blockIdx.y * 128, n0 = blockIdx.x * 128;
    const int wm = (wave >> 1) * 64, wn = (wave & 1) * 64;
    const int srow = wave * 32;                  // 32 staged rows per wave
    const int row8 = lane >> 3;                  // 0..7 within 8-row group
    const int grp  = ((lane & 7) ^ row8) * 8;    // swizzled col offset (u16)
    f32x4 acc[4][4] = {};

    const u16* pa;
    {
        int m = m0 + srow + row8;
        if (AMAP == 0) pa = A + (size_t)m * K + grp;
        else {
            int hr = (m >> 10) * TPAD + (m & 1023) + (AMAP == 1 ? 4 : 0);
            pa = A + (size_t)hr * D_ + grp;
        }
    }
    const u16* pb = W + (size_t)(n0 + srow + row8) * K + grp;
    constexpr size_t rsA = (AMAP == 0) ? (size_t)K : (size_t)D_;
    constexpr size_t rsB = (size_t)K;

    u16* lda = &As[srow * 64];
    u16* ldb = &Bs[srow * 64];
    const int rg = (quad ^ (l15 & 7)) * 8;       // read col group (u16 offset)

    int kpos = 0;
    constexpr int nkt = K / 64;
    for (int t = 0; t < nkt; t++) {
#pragma unroll
        for (int q = 0; q < 4; q++) {
            glds16(pa + (size_t)q * 8 * rsA, lda + q * 8 * 64);
            glds16(pb + (size_t)q * 8 * rsB, ldb + q * 8 * 64);
        }
        if (AMAP == 2) {
            if (kpos == 8) { kpos = 0; pa += 64 - 8 * 256; pb += 64 - 8 * 256; }
            else           { kpos++;  pa += 256;           pb += 256; }
        } else { pa += 64; pb += 64; }
        __builtin_amdgcn_s_waitcnt(0);
        __syncthreads();
#pragma unroll
        for (int ks = 0; ks < 2; ks++) {
            bf16x8 af[4], bfr[4];
#pragma unroll
            for (int i = 0; i < 4; i++)
                af[i] = *(const bf16x8*)&As[(wm + i * 16 + l15) * 64 + (rg ^ (ks * 32))];
#pragma unroll
            for (int j = 0; j < 4; j++)
                bfr[j] = *(const bf16x8*)&Bs[(wn + j * 16 + l15) * 64 + (rg ^ (ks * 32))];
#pragma unroll
            for (int i = 0; i < 4; i++)
#pragma unroll
                for (int j = 0; j < 4; j++)
                    acc[i][j] = __builtin_amdgcn_mfma_f32_16x16x32_bf16(
                        af[i], bfr[j], acc[i][j], 0, 0, 0);
        }
        __syncthreads();
    }

    float bv[4];
#pragma unroll
    for (int j = 0; j < 4; j++) bv[j] = bf2f(bias[n0 + wn + j * 16 + l15]);
#pragma unroll
    for (int i = 0; i < 4; i++) {
#pragma unroll
        for (int r = 0; r < 4; r++) {
            int m = m0 + wm + i * 16 + quad * 4 + r;
            float mk = (EPI == 2) ? mask[m] : 1.0f;
#pragma unroll
            for (int j = 0; j < 4; j++) {
                int n = n0 + wn + j * 16 + l15;
                float v = acc[i][j][r] + bv[j];
                if (EPI == 1) v = fmaxf(v, 0.0f);
                if (EPI == 2) {
                    v = (v + resid[(size_t)m * N + n]) * mk;
                    ((float*)Cp)[(size_t)m * N + n] = v;
                } else {
                    ((u16*)Cp)[(size_t)m * N + n] = f2bf(v);
                }
            }
        }
    }
}

// --------------------------- flash MFMA attention --------------------------
// QKV [Mc][768] bf16 (q|k|v, head h at cols h*128).
// Grid: (hb = h + 2*b  [fastest -> same-XCD for shared K/V], qt). 256 thr,
// 64 q/block (16/wave), K-tiles of 64 keys, online softmax, O -> Hpad bf16.
// LDS ~40KB: Ks 64x136 (Ps aliased in after QK), Vt 128x72 swizzled, npS 4KB.
__global__ __launch_bounds__(256)
void attn_mfma(const u16* __restrict__ QKV, const float* __restrict__ NPg,
               u16* __restrict__ Hp) {
    __shared__ __align__(16) u16 KsPs[64 * 136];   // Ks; aliased as Ps post-QK
    __shared__ __align__(16) u16 Vt[128 * 72];
    __shared__ float npS[1024];
    u16* Ks  = KsPs;
    const int tid  = threadIdx.x;
    const int wave = tid >> 6, lane = tid & 63;
    const int quad = lane >> 4, l15 = lane & 15;
    const int hb = blockIdx.x;
    const int h = hb & (NH_ - 1), b = hb >> 1;
    const int qt = blockIdx.y;
    const int t0 = qt * 64;
    const float scale = 0.08838834764831845f;  // 1/sqrt(128)
    u16* Psw = KsPs + wave * 16 * 72;

    for (int i = tid; i < 1024; i += 256) npS[i] = NPg[b * 1024 + i];

    bf16x8 q_a[4];
#pragma unroll
    for (int s = 0; s < 4; s++)
        q_a[s] = *(const bf16x8*)(QKV
            + (size_t)(b * 1024 + t0 + wave * 16 + l15) * 768
            + h * DK_ + s * 32 + quad * 8);

    float m_st[4], l_st[4];
    f32x4 oacc[8] = {};
#pragma unroll
    for (int r = 0; r < 4; r++) { m_st[r] = -1e30f; l_st[r] = 0.0f; }

    for (int kk = 0; kk < 16; kk++) {
        const int k0 = kk * 64;
        if (kk) __syncthreads();   // prev tile's PV reads (Ps alias, Vt) done
#pragma unroll
        for (int p = 0; p < 4; p++) {
            int s = tid + p * 256;
            int key = s >> 4, dk0 = (s & 15) * 8;
            size_t grow = (size_t)(b * 1024 + k0 + key) * 768 + h * DK_;
            *(u16x8*)&Ks[key * 136 + dk0] = *(const u16x8*)(QKV + grow + 256 + dk0);
            u16x8 vv = *(const u16x8*)(QKV + grow + 512 + dk0);
            int colb = key ^ ((s & 7) << 3);
#pragma unroll
            for (int e = 0; e < 8; e++) Vt[(dk0 + e) * 72 + colb] = vv[e];
        }
        __syncthreads();

        f32x4 s4[4];
#pragma unroll
        for (int nt = 0; nt < 4; nt++) {
            f32x4 c = {0.f, 0.f, 0.f, 0.f};
#pragma unroll
            for (int s = 0; s < 4; s++) {
                bf16x8 kb = *(const bf16x8*)&Ks[(nt * 16 + l15) * 136 + s * 32 + quad * 8];
                c = __builtin_amdgcn_mfma_f32_16x16x32_bf16(q_a[s], kb, c, 0, 0, 0);
            }
            s4[nt] = c;
        }
        __syncthreads();           // all QK reads of Ks done; Ks area -> Ps

#pragma unroll
        for (int nt = 0; nt < 4; nt++) {
            bool pad = (npS[k0 + nt * 16 + l15] == 0.0f);
#pragma unroll
            for (int r = 0; r < 4; r++)
                s4[nt][r] = pad ? -1e30f : s4[nt][r] * scale;
        }
        float alpha[4];
#pragma unroll
        for (int r = 0; r < 4; r++) {
            float v = fmaxf(fmaxf(s4[0][r], s4[1][r]), fmaxf(s4[2][r], s4[3][r]));
#pragma unroll
            for (int d = 1; d < 16; d <<= 1) v = fmaxf(v, __shfl_xor(v, d, 64));
            float mnew = fmaxf(m_st[r], v);
            alpha[r] = __expf(m_st[r] - mnew);
            m_st[r] = mnew;
            l_st[r] *= alpha[r];
        }
#pragma unroll
        for (int nt = 0; nt < 4; nt++)
#pragma unroll
            for (int r = 0; r < 4; r++) s4[nt][r] = __expf(s4[nt][r] - m_st[r]);
#pragma unroll
        for (int r = 0; r < 4; r++) {
            float v = s4[0][r] + s4[1][r] + s4[2][r] + s4[3][r];
#pragma unroll
            for (int d = 1; d < 16; d <<= 1) v += __shfl_xor(v, d, 64);
            l_st[r] += v;
        }
#pragma unroll
        for (int dt = 0; dt < 8; dt++)
#pragma unroll
            for (int r = 0; r < 4; r++) oacc[dt][r] *= alpha[r];
#pragma unroll
        for (int nt = 0; nt < 4; nt++)
#pragma unroll
            for (int r = 0; r < 4; r++)
                Psw[(quad * 4 + r) * 72 + nt * 16 + l15] = f2bf(s4[nt][r]);
#pragma unroll
        for (int ks = 0; ks < 2; ks++) {
            bf16x8 pa = *(const bf16x8*)&Psw[l15 * 72 + ks * 32 + quad * 8];
#pragma unroll
            for (int dt = 0; dt < 8; dt++) {
                int d = dt * 16 + l15;
                int swr = ((d >> 3) & 7) << 3;
                bf16x8 vb = *(const bf16x8*)&Vt[d * 72 + ((ks * 32 + quad * 8) ^ swr)];
                oacc[dt] = __builtin_amdgcn_mfma_f32_16x16x32_bf16(pa, vb, oacc[dt], 0, 0, 0);
            }
        }
    }

#pragma unroll
    for (int r = 0; r < 4; r++) {
        float inv = 1.0f / l_st[r];
        int t = t0 + wave * 16 + quad * 4 + r;
        size_t orow = (size_t)(b * TPAD + 4 + t) * D_ + h * DK_;
#pragma unroll
        for (int dt = 0; dt < 8; dt++)
            Hp[orow + dt * 16 + l15] = f2bf(oacc[dt][r] * inv);
    }
}

// ------------------------------- driver ------------------------------------

static inline int cdiv(int a, int b) { return (a + b - 1) / b; }

extern "C" void kernel_launch(void* const* d_in, const int* in_sizes, int n_in,
                              void* d_out, int out_size, void* d_ws, size_t ws_size,
                              hipStream_t stream) {
    const int* seq = (const int*)d_in[0];
    const int* pos = (const int*)d_in[1];
    (void)in_sizes; (void)n_in;

    int   cb = 8, w1L = 1;
    int*   FLAG; float* X; float* NP; u16* Hpad; u16* SCR; u16* W1R;
    u16 *WEMB, *PEMB, *QKVW, *QKVB, *FCW, *FCB, *G1c, *B1c, *C1B, *C2W, *C2B, *G2c, *B2c;

    unsigned char* wsb = (unsigned char*)d_ws;
    size_t off;
    auto build = [&](int cb_, int w1L_) -> size_t {
        off = 0;
        auto take = [&](size_t bytes) {
            unsigned char* p = wsb + off;
            off += (bytes + 255) & ~(size_t)255;
            return p;
        };
        FLAG = (int*)  take(4);
        X    = (float*)take((size_t)MROWS * D_ * 4);
        NP   = (float*)take((size_t)MROWS * 4);
        Hpad = (u16*)  take((size_t)cb_ * TPAD * D_ * 2);
        SCR  = (u16*)  take((size_t)cb_ * T_ * DH_ * 2);
        W1R  = (u16*)  take((size_t)w1L_ * DH_ * KCONV * 2);
        WEMB = (u16*)  take((size_t)300 * D_ * 2);
        PEMB = (u16*)  take((size_t)3001 * D_ * 2);
        QKVW = (u16*)  take((size_t)L_ * 3 * D_ * D_ * 2);
        QKVB = (u16*)  take((size_t)L_ * 3 * D_ * 2);
        FCW  = (u16*)  take((size_t)L_ * D_ * D_ * 2);
        FCB  = (u16*)  take((size_t)L_ * D_ * 2);
        G1c  = (u16*)  take((size_t)L_ * D_ * 2);
        B1c  = (u16*)  take((size_t)L_ * D_ * 2);
        C1B  = (u16*)  take((size_t)L_ * DH_ * 2);
        C2W  = (u16*)  take((size_t)L_ * D_ * DH_ * 2);
        C2B  = (u16*)  take((size_t)L_ * D_ * 2);
        G2c  = (u16*)  take((size_t)L_ * D_ * 2);
        B2c  = (u16*)  take((size_t)L_ * D_ * 2);
        return off;
    };
    if      (build(32, L_) <= ws_size) { cb = 32; w1L = L_; }
    else if (build(8,  L_) <= ws_size) { cb = 8;  w1L = L_; }
    else if (build(8,  1)  <= ws_size) { cb = 8;  w1L = 1;  }
    else {
        sentinel_kernel<<<cdiv(out_size, 256), 256, 0, stream>>>(d_out, out_size);
        return;
    }
    const int nch = B_ / cb;
    const int Mc  = cb * T_;

    detect_kernel<<<1, 256, 0, stream>>>(d_in[2], FLAG);
    auto cvt = [&](const void* src, u16* dst, int n) {
        cvt_any_kernel<<<cdiv(n, 256), 256, 0, stream>>>(src, dst, n, FLAG);
    };
    cvt(d_in[2],  WEMB, 300 * D_);
    cvt(d_in[3],  PEMB, 3001 * D_);
    cvt(d_in[4],  QKVW, L_ * 3 * D_ * D_);
    cvt(d_in[5],  QKVB, L_ * 3 * D_);
    cvt(d_in[6],  FCW,  L_ * D_ * D_);
    cvt(d_in[7],  FCB,  L_ * D_);
    cvt(d_in[8],  G1c,  L_ * D_);
    cvt(d_in[9],  B1c,  L_ * D_);
    cvt(d_in[11], C1B,  L_ * DH_);
    cvt(d_in[12], C2W,  L_ * D_ * DH_);
    cvt(d_in[13], C2B,  L_ * D_);
    cvt(d_in[14], G2c,  L_ * D_);
    cvt(d_in[15], B2c,  L_ * D_);
    if (w1L == L_) {
        int n = L_ * DH_ * KCONV;
        w1_reorder2_kernel<<<cdiv(n, 256), 256, 0, stream>>>(
            (const float*)d_in[10], (const u16*)d_in[10], W1R, n, FLAG);
    }

    embed_kernel<<<MROWS, 256, 0, stream>>>(seq, pos, WEMB, PEMB, X, NP);
    zero_pad_kernel<<<cb * 8, 256, 0, stream>>>(Hpad, cb);

    for (int l = 0; l < L_; l++) {
        for (int c = 0; c < nch; c++) {
            const size_t ro = (size_t)c * Mc;
            ln_kernel<<<Mc / 4, 256, 0, stream>>>(
                X + ro * D_, G1c + l * D_, B1c + l * D_, Hpad);
            gemm_mfma<1, 0, 256><<<dim3(6, Mc / 128), 256, 0, stream>>>(
                Hpad, QKVW + (size_t)l * 3 * D_ * D_, QKVB + l * 3 * D_,
                nullptr, nullptr, SCR, Mc, 3 * D_);
            attn_mfma<<<dim3(NH_ * cb, 16), 256, 0, stream>>>(
                SCR, NP + ro, Hpad);
            gemm_mfma<1, 2, 256><<<dim3(2, Mc / 128), 256, 0, stream>>>(
                Hpad, FCW + (size_t)l * D_ * D_, FCB + l * D_,
                X + ro * D_, NP + ro, X + ro * D_, Mc, D_);
        }
        const u16* w1p = W1R + (w1L == L_ ? (size_t)l * DH_ * KCONV : 0);
        if (w1L != L_) {
            int n = DH_ * KCONV;
            w1_reorder2_kernel<<<cdiv(n, 256), 256, 0, stream>>>(
                (const float*)d_in[10] + (size_t)l * DH_ * D_ * 9,
                (const u16*)d_in[10] + (size_t)l * DH_ * D_ * 9,
                W1R, n, FLAG);
        }
        for (int c = 0; c < nch; c++) {
            const size_t ro = (size_t)c * Mc;
            ln_kernel<<<Mc / 4, 256, 0, stream>>>(
                X + ro * D_, G2c + l * D_, B2c + l * D_, Hpad);
            gemm_mfma<2, 1, 2304><<<dim3(8, Mc / 128), 256, 0, stream>>>(
                Hpad, w1p, C1B + l * DH_,
                nullptr, nullptr, SCR, Mc, DH_);
            gemm_mfma<0, 2, 1024><<<dim3(2, Mc / 128), 256, 0, stream>>>(
                SCR, C2W + (size_t)l * D_ * DH_, C2B + l * D_,
                X + ro * D_, NP + ro, X + ro * D_, Mc, D_);
        }
    }

    out_kernel<<<cdiv(out_size, 256), 256, 0, stream>>>(X, NP, d_out, out_size, FLAG);
}

// Round 9
// 1688.081 us; speedup vs baseline: 1.1623x; 1.1007x over previous
//
#include <hip/hip_runtime.h>

// ---------------------------------------------------------------------------
// FastSpeech-style encoder, round 8:
//  - Attention: 128 q/block (2 sub-tiles per wave) -> staging/barrier cost
//    amortized over 2x MFMA; register prefetch of next K/V tile hides L2
//    latency. Grid (hb fastest for XCD locality, qt=8).
//  - GEMMs: round-7 BK=64 structure (conflict-free, conv1 at plateau).
// B=32 T=1024 D=256 NH=2 dk=128 D_HID=1024 L=4, conv1 k9p4, conv2 k1.
// ---------------------------------------------------------------------------

#define B_ 32
#define T_ 1024
#define D_ 256
#define NH_ 2
#define DK_ 128
#define DH_ 1024
#define L_ 4
#define MROWS (B_ * T_)        // 32768
#define KCONV (D_ * 9)         // 2304
#define TPAD 1032              // 4 zero + 1024 + 4 zero rows per batch (Hpad)

typedef unsigned short u16;
typedef short bf16x8 __attribute__((ext_vector_type(8)));
typedef float f32x4 __attribute__((ext_vector_type(4)));
typedef u16 u16x8 __attribute__((ext_vector_type(8)));

__device__ __forceinline__ float bf2f(u16 h) {
    union { unsigned int u; float f; } a;
    a.u = ((unsigned int)h) << 16;
    return a.f;
}

__device__ __forceinline__ u16 f2bf(float f) {
    union { float f; unsigned int u; } a;
    a.f = f;
    unsigned int r = a.u + 0x7fffu + ((a.u >> 16) & 1u);  // RNE
    return (u16)(r >> 16);
}

__device__ __forceinline__ void glds16(const u16* g, u16* l) {
    __builtin_amdgcn_global_load_lds(
        (const __attribute__((address_space(1))) void*)g,
        (__attribute__((address_space(3))) void*)l, 16, 0, 0);
}

// --------------------------- dtype detection -------------------------------
__global__ void detect_kernel(const void* wemb_raw, int* flag) {
    __shared__ int cnt;
    if (threadIdx.x == 0) cnt = 0;
    __syncthreads();
    const u16* p = (const u16*)wemb_raw;
    if (p[256 + threadIdx.x] != 0) atomicAdd(&cnt, 1);
    __syncthreads();
    if (threadIdx.x == 0) *flag = (cnt >= 128) ? 1 : 0;   // 1 = bf16, 0 = fp32
}

__global__ void cvt_any_kernel(const void* __restrict__ src, u16* __restrict__ dst,
                               int n, const int* __restrict__ flag) {
    int i = blockIdx.x * 256 + threadIdx.x;
    if (i >= n) return;
    if (*flag) dst[i] = ((const u16*)src)[i];
    else       dst[i] = f2bf(((const float*)src)[i]);
}

// conv1 weights [l][oc][ic=256][kpos=9] -> [l][oc][kpos*256+ic] bf16
__global__ void w1_reorder2_kernel(const float* __restrict__ srcf,
                                   const u16* __restrict__ srch,
                                   u16* __restrict__ out, int n,
                                   const int* __restrict__ flag) {
    int idx = blockIdx.x * 256 + threadIdx.x;
    if (idx >= n) return;
    int l  = idx / (DH_ * KCONV);
    int r  = idx % (DH_ * KCONV);
    int oc = r / KCONV;
    int kk = r % KCONV;
    int kpos = kk >> 8;
    int ic   = kk & 255;
    size_t si = (size_t)l * DH_ * D_ * 9 + (oc * D_ + ic) * 9 + kpos;
    out[idx] = (*flag) ? srch[si] : f2bf(srcf[si]);
}

__global__ void sentinel_kernel(void* out, int out_size) {
    int i = blockIdx.x * 256 + threadIdx.x;
    if (i < out_size) ((u16*)out)[i] = 0x42F6;  // 123.0 bf16 — "ws too small"
}

// --------------------------- small utility kernels -------------------------

__global__ void embed_kernel(const int* __restrict__ seq, const int* __restrict__ pos,
                             const u16* __restrict__ wemb, const u16* __restrict__ pemb,
                             float* __restrict__ X, float* __restrict__ NP) {
    int row = blockIdx.x;
    int d   = threadIdx.x;
    int s = seq[row];
    int p = pos[row];
    X[(size_t)row * D_ + d] = bf2f(wemb[s * D_ + d]) + bf2f(pemb[p * D_ + d]);
    if (d == 0) NP[row] = (s != 0) ? 1.0f : 0.0f;
}

__global__ void zero_pad_kernel(u16* __restrict__ Hp, int nb) {
    int i = blockIdx.x * 256 + threadIdx.x;
    if (i >= nb * 8 * 256) return;
    int b = i / (8 * 256);
    int r = (i / 256) & 7;
    int d = i & 255;
    int row = (r < 4) ? r : (1024 + r);
    Hp[(size_t)(b * TPAD + row) * D_ + d] = 0;
}

// LN: 4 rows/block (1 wave/row); out -> Hpad layout.
__global__ __launch_bounds__(256)
void ln_kernel(const float* __restrict__ x, const u16* __restrict__ g,
               const u16* __restrict__ bta, u16* __restrict__ outp) {
    int wave = threadIdx.x >> 6, lane = threadIdx.x & 63;
    int row = blockIdx.x * 4 + wave;
    const float* xr = x + (size_t)row * D_;
    float4 v = *(const float4*)&xr[lane * 4];
    float s  = v.x + v.y + v.z + v.w;
    float s2 = v.x * v.x + v.y * v.y + v.z * v.z + v.w * v.w;
#pragma unroll
    for (int d = 1; d < 64; d <<= 1) {
        s  += __shfl_xor(s,  d, 64);
        s2 += __shfl_xor(s2, d, 64);
    }
    float m   = s * (1.0f / 256.0f);
    float var = s2 * (1.0f / 256.0f) - m * m;
    float rr  = rsqrtf(var + 1e-5f);
    size_t orow = (size_t)((row >> 10) * TPAD + 4 + (row & 1023)) * D_;
    float vv[4] = {v.x, v.y, v.z, v.w};
#pragma unroll
    for (int k = 0; k < 4; k++) {
        int d = lane * 4 + k;
        outp[orow + d] = f2bf((vv[k] - m) * rr * bf2f(g[d]) + bf2f(bta[d]));
    }
}

__global__ void out_kernel(const float* __restrict__ X, const float* __restrict__ NP,
                           void* __restrict__ out, int out_size,
                           const int* __restrict__ flag) {
    int i = blockIdx.x * 256 + threadIdx.x;
    if (i >= out_size) return;
    const int n1 = MROWS * D_;
    float v = (i < n1) ? X[i] : NP[i - n1];
    if (*flag) ((u16*)out)[i] = f2bf(v);
    else       ((float*)out)[i] = v;
}

// ------------------------------- MFMA GEMM ---------------------------------
// C[M,N] = A[M,K] @ W^T, W: [N][K] bf16 row-major. 128x128 tile, BK=64,
// 256 threads (2x2 waves of 64x64, each 4x4 MFMA tiles of 16x16x32, 2 k-subs).
// AMAP: 0 plain A[M][K]; 1 Hpad rows (K=256); 2 Hpad im2col (K=2304,
//       kpos-inner walk: pointer +256/iter, rollover +64-2048).
// EPI:  0 bf16 (+bias); 1 bf16 (+bias, relu); 2 fp32 (+bias, +resid, *mask).
template <int AMAP, int EPI, int K>
__global__ __launch_bounds__(256)
void gemm_mfma(const u16* __restrict__ A, const u16* __restrict__ W,
               const u16* __restrict__ bias, const float* __restrict__ resid,
               const float* __restrict__ mask, void* __restrict__ Cp,
               int M, int N) {
    __shared__ __align__(16) u16 As[128 * 64];
    __shared__ __align__(16) u16 Bs[128 * 64];
    const int tid  = threadIdx.x;
    const int wave = tid >> 6, lane = tid & 63;
    const int quad = lane >> 4, l15 = lane & 15;
    const int m0 = blockIdx.y * 128, n0 = blockIdx.x * 128;
    const int wm = (wave >> 1) * 64, wn = (wave & 1) * 64;
    const int srow = wave * 32;                  // 32 staged rows per wave
    const int row8 = lane >> 3;                  // 0..7 within 8-row group
    const int grp  = ((lane & 7) ^ row8) * 8;    // swizzled col offset (u16)
    f32x4 acc[4][4] = {};

    const u16* pa;
    {
        int m = m0 + srow + row8;
        if (AMAP == 0) pa = A + (size_t)m * K + grp;
        else {
            int hr = (m >> 10) * TPAD + (m & 1023) + (AMAP == 1 ? 4 : 0);
            pa = A + (size_t)hr * D_ + grp;
        }
    }
    const u16* pb = W + (size_t)(n0 + srow + row8) * K + grp;
    constexpr size_t rsA = (AMAP == 0) ? (size_t)K : (size_t)D_;
    constexpr size_t rsB = (size_t)K;

    u16* lda = &As[srow * 64];
    u16* ldb = &Bs[srow * 64];
    const int rg = (quad ^ (l15 & 7)) * 8;       // read col group (u16 offset)

    int kpos = 0;
    constexpr int nkt = K / 64;
    for (int t = 0; t < nkt; t++) {
#pragma unroll
        for (int q = 0; q < 4; q++) {
            glds16(pa + (size_t)q * 8 * rsA, lda + q * 8 * 64);
            glds16(pb + (size_t)q * 8 * rsB, ldb + q * 8 * 64);
        }
        if (AMAP == 2) {
            if (kpos == 8) { kpos = 0; pa += 64 - 8 * 256; pb += 64 - 8 * 256; }
            else           { kpos++;  pa += 256;           pb += 256; }
        } else { pa += 64; pb += 64; }
        __builtin_amdgcn_s_waitcnt(0);
        __syncthreads();
#pragma unroll
        for (int ks = 0; ks < 2; ks++) {
            bf16x8 af[4], bfr[4];
#pragma unroll
            for (int i = 0; i < 4; i++)
                af[i] = *(const bf16x8*)&As[(wm + i * 16 + l15) * 64 + (rg ^ (ks * 32))];
#pragma unroll
            for (int j = 0; j < 4; j++)
                bfr[j] = *(const bf16x8*)&Bs[(wn + j * 16 + l15) * 64 + (rg ^ (ks * 32))];
#pragma unroll
            for (int i = 0; i < 4; i++)
#pragma unroll
                for (int j = 0; j < 4; j++)
                    acc[i][j] = __builtin_amdgcn_mfma_f32_16x16x32_bf16(
                        af[i], bfr[j], acc[i][j], 0, 0, 0);
        }
        __syncthreads();
    }

    float bv[4];
#pragma unroll
    for (int j = 0; j < 4; j++) bv[j] = bf2f(bias[n0 + wn + j * 16 + l15]);
#pragma unroll
    for (int i = 0; i < 4; i++) {
#pragma unroll
        for (int r = 0; r < 4; r++) {
            int m = m0 + wm + i * 16 + quad * 4 + r;
            float mk = (EPI == 2) ? mask[m] : 1.0f;
#pragma unroll
            for (int j = 0; j < 4; j++) {
                int n = n0 + wn + j * 16 + l15;
                float v = acc[i][j][r] + bv[j];
                if (EPI == 1) v = fmaxf(v, 0.0f);
                if (EPI == 2) {
                    v = (v + resid[(size_t)m * N + n]) * mk;
                    ((float*)Cp)[(size_t)m * N + n] = v;
                } else {
                    ((u16*)Cp)[(size_t)m * N + n] = f2bf(v);
                }
            }
        }
    }
}

// --------------------------- flash MFMA attention --------------------------
// QKV [Mc][768] bf16 (q|k|v, head h at cols h*128).
// Grid: (hb = h + 2*b [fastest -> XCD locality], qt8 0..7). 256 thr.
// 128 q/block: each wave owns q rows {qt8*128 + wave*16 (+64)} (2 sub-tiles).
// K-tiles of 64 keys; register prefetch of next tile; online softmax;
// O -> Hpad bf16. LDS ~40KB: Ks 64x136 (Ps aliased post-QK), Vt 128x72, npS.
__global__ __launch_bounds__(256, 2)
void attn_mfma(const u16* __restrict__ QKV, const float* __restrict__ NPg,
               u16* __restrict__ Hp) {
    __shared__ __align__(16) u16 KsPs[64 * 136];   // Ks; aliased as Ps post-QK
    __shared__ __align__(16) u16 Vt[128 * 72];
    __shared__ float npS[1024];
    u16* Ks  = KsPs;
    const int tid  = threadIdx.x;
    const int wave = tid >> 6, lane = tid & 63;
    const int quad = lane >> 4, l15 = lane & 15;
    const int hb = blockIdx.x;
    const int h = hb & (NH_ - 1), b = hb >> 1;
    const int qt8 = blockIdx.y;
    const int t0 = qt8 * 128;
    const float scale = 0.08838834764831845f;  // 1/sqrt(128)
    u16* Psw = KsPs + wave * 16 * 72;

    for (int i = tid; i < 1024; i += 256) npS[i] = NPg[b * 1024 + i];

    bf16x8 q_a[2][4];
#pragma unroll
    for (int sub = 0; sub < 2; sub++)
#pragma unroll
        for (int s = 0; s < 4; s++)
            q_a[sub][s] = *(const bf16x8*)(QKV
                + (size_t)(b * 1024 + t0 + sub * 64 + wave * 16 + l15) * 768
                + h * DK_ + s * 32 + quad * 8);

    float m_st[2][4], l_st[2][4];
    f32x4 oacc[2][8] = {};
#pragma unroll
    for (int sub = 0; sub < 2; sub++)
#pragma unroll
        for (int r = 0; r < 4; r++) { m_st[sub][r] = -1e30f; l_st[sub][r] = 0.0f; }

    // prefetch registers for K/V tiles
    u16x8 kpre[4], vpre[4];
    const int skey = tid >> 4;             // base key row this thread stages
    const int dk0  = (tid & 15) * 8;
    const int colb0 = ((tid & 7) << 3);    // XOR'd with key at store time
#pragma unroll
    for (int p = 0; p < 4; p++) {
        size_t grow = (size_t)(b * 1024 + 0 + skey + p * 16) * 768 + h * DK_;
        kpre[p] = *(const u16x8*)(QKV + grow + 256 + dk0);
        vpre[p] = *(const u16x8*)(QKV + grow + 512 + dk0);
    }

    for (int kk = 0; kk < 16; kk++) {
        const int k0 = kk * 64;
        if (kk) __syncthreads();   // prior tile's PV reads + Ps writes done
        // ---- stage prefetched regs -> LDS ----
#pragma unroll
        for (int p = 0; p < 4; p++) {
            int key = skey + p * 16;
            *(u16x8*)&Ks[key * 136 + dk0] = kpre[p];
            int colb = key ^ colb0;
#pragma unroll
            for (int e = 0; e < 8; e++) Vt[(dk0 + e) * 72 + colb] = vpre[p][e];
        }
        __syncthreads();
        // ---- issue next tile's loads (consumed next iteration) ----
        if (kk < 15) {
#pragma unroll
            for (int p = 0; p < 4; p++) {
                size_t grow = (size_t)(b * 1024 + k0 + 64 + skey + p * 16) * 768 + h * DK_;
                kpre[p] = *(const u16x8*)(QKV + grow + 256 + dk0);
                vpre[p] = *(const u16x8*)(QKV + grow + 512 + dk0);
            }
        }

        // ---- S = Q K^T for both sub-tiles (reads Ks) ----
        f32x4 s4[2][4];
#pragma unroll
        for (int sub = 0; sub < 2; sub++)
#pragma unroll
            for (int nt = 0; nt < 4; nt++) {
                f32x4 c = {0.f, 0.f, 0.f, 0.f};
#pragma unroll
                for (int s = 0; s < 4; s++) {
                    bf16x8 kb = *(const bf16x8*)&Ks[(nt * 16 + l15) * 136 + s * 32 + quad * 8];
                    c = __builtin_amdgcn_mfma_f32_16x16x32_bf16(q_a[sub][s], kb, c, 0, 0, 0);
                }
                s4[sub][nt] = c;
            }
        __syncthreads();           // Ks reads done; Ks area becomes Ps

#pragma unroll
        for (int sub = 0; sub < 2; sub++) {
            // ---- mask + scale ----
#pragma unroll
            for (int nt = 0; nt < 4; nt++) {
                bool pad = (npS[k0 + nt * 16 + l15] == 0.0f);
#pragma unroll
                for (int r = 0; r < 4; r++)
                    s4[sub][nt][r] = pad ? -1e30f : s4[sub][nt][r] * scale;
            }
            // ---- online softmax ----
            float alpha[4];
#pragma unroll
            for (int r = 0; r < 4; r++) {
                float v = fmaxf(fmaxf(s4[sub][0][r], s4[sub][1][r]),
                                fmaxf(s4[sub][2][r], s4[sub][3][r]));
#pragma unroll
                for (int d = 1; d < 16; d <<= 1) v = fmaxf(v, __shfl_xor(v, d, 64));
                float mnew = fmaxf(m_st[sub][r], v);
                alpha[r] = __expf(m_st[sub][r] - mnew);
                m_st[sub][r] = mnew;
                l_st[sub][r] *= alpha[r];
            }
#pragma unroll
            for (int nt = 0; nt < 4; nt++)
#pragma unroll
                for (int r = 0; r < 4; r++)
                    s4[sub][nt][r] = __expf(s4[sub][nt][r] - m_st[sub][r]);
#pragma unroll
            for (int r = 0; r < 4; r++) {
                float v = s4[sub][0][r] + s4[sub][1][r] + s4[sub][2][r] + s4[sub][3][r];
#pragma unroll
                for (int d = 1; d < 16; d <<= 1) v += __shfl_xor(v, d, 64);
                l_st[sub][r] += v;
            }
#pragma unroll
            for (int dt = 0; dt < 8; dt++)
#pragma unroll
                for (int r = 0; r < 4; r++) oacc[sub][dt][r] *= alpha[r];
            // ---- P -> per-wave LDS (wave-private; in-order DS per wave) ----
#pragma unroll
            for (int nt = 0; nt < 4; nt++)
#pragma unroll
                for (int r = 0; r < 4; r++)
                    Psw[(quad * 4 + r) * 72 + nt * 16 + l15] = f2bf(s4[sub][nt][r]);
            // ---- O += P V ----
#pragma unroll
            for (int ks = 0; ks < 2; ks++) {
                bf16x8 pa = *(const bf16x8*)&Psw[l15 * 72 + ks * 32 + quad * 8];
#pragma unroll
                for (int dt = 0; dt < 8; dt++) {
                    int d = dt * 16 + l15;
                    int swr = ((d >> 3) & 7) << 3;
                    bf16x8 vb = *(const bf16x8*)&Vt[d * 72 + ((ks * 32 + quad * 8) ^ swr)];
                    oacc[sub][dt] = __builtin_amdgcn_mfma_f32_16x16x32_bf16(
                        pa, vb, oacc[sub][dt], 0, 0, 0);
                }
            }
        }
    }

    // ---- epilogue: O / l -> Hpad ----
#pragma unroll
    for (int sub = 0; sub < 2; sub++)
#pragma unroll
        for (int r = 0; r < 4; r++) {
            float inv = 1.0f / l_st[sub][r];
            int t = t0 + sub * 64 + wave * 16 + quad * 4 + r;
            size_t orow = (size_t)(b * TPAD + 4 + t) * D_ + h * DK_;
#pragma unroll
            for (int dt = 0; dt < 8; dt++)
                Hp[orow + dt * 16 + l15] = f2bf(oacc[sub][dt][r] * inv);
        }
}

// ------------------------------- driver ------------------------------------

static inline int cdiv(int a, int b) { return (a + b - 1) / b; }

extern "C" void kernel_launch(void* const* d_in, const int* in_sizes, int n_in,
                              void* d_out, int out_size, void* d_ws, size_t ws_size,
                              hipStream_t stream) {
    const int* seq = (const int*)d_in[0];
    const int* pos = (const int*)d_in[1];
    (void)in_sizes; (void)n_in;

    int   cb = 8, w1L = 1;
    int*   FLAG; float* X; float* NP; u16* Hpad; u16* SCR; u16* W1R;
    u16 *WEMB, *PEMB, *QKVW, *QKVB, *FCW, *FCB, *G1c, *B1c, *C1B, *C2W, *C2B, *G2c, *B2c;

    unsigned char* wsb = (unsigned char*)d_ws;
    size_t off;
    auto build = [&](int cb_, int w1L_) -> size_t {
        off = 0;
        auto take = [&](size_t bytes) {
            unsigned char* p = wsb + off;
            off += (bytes + 255) & ~(size_t)255;
            return p;
        };
        FLAG = (int*)  take(4);
        X    = (float*)take((size_t)MROWS * D_ * 4);
        NP   = (float*)take((size_t)MROWS * 4);
        Hpad = (u16*)  take((size_t)cb_ * TPAD * D_ * 2);
        SCR  = (u16*)  take((size_t)cb_ * T_ * DH_ * 2);
        W1R  = (u16*)  take((size_t)w1L_ * DH_ * KCONV * 2);
        WEMB = (u16*)  take((size_t)300 * D_ * 2);
        PEMB = (u16*)  take((size_t)3001 * D_ * 2);
        QKVW = (u16*)  take((size_t)L_ * 3 * D_ * D_ * 2);
        QKVB = (u16*)  take((size_t)L_ * 3 * D_ * 2);
        FCW  = (u16*)  take((size_t)L_ * D_ * D_ * 2);
        FCB  = (u16*)  take((size_t)L_ * D_ * 2);
        G1c  = (u16*)  take((size_t)L_ * D_ * 2);
        B1c  = (u16*)  take((size_t)L_ * D_ * 2);
        C1B  = (u16*)  take((size_t)L_ * DH_ * 2);
        C2W  = (u16*)  take((size_t)L_ * D_ * DH_ * 2);
        C2B  = (u16*)  take((size_t)L_ * D_ * 2);
        G2c  = (u16*)  take((size_t)L_ * D_ * 2);
        B2c  = (u16*)  take((size_t)L_ * D_ * 2);
        return off;
    };
    if      (build(32, L_) <= ws_size) { cb = 32; w1L = L_; }
    else if (build(8,  L_) <= ws_size) { cb = 8;  w1L = L_; }
    else if (build(8,  1)  <= ws_size) { cb = 8;  w1L = 1;  }
    else {
        sentinel_kernel<<<cdiv(out_size, 256), 256, 0, stream>>>(d_out, out_size);
        return;
    }
    const int nch = B_ / cb;
    const int Mc  = cb * T_;

    detect_kernel<<<1, 256, 0, stream>>>(d_in[2], FLAG);
    auto cvt = [&](const void* src, u16* dst, int n) {
        cvt_any_kernel<<<cdiv(n, 256), 256, 0, stream>>>(src, dst, n, FLAG);
    };
    cvt(d_in[2],  WEMB, 300 * D_);
    cvt(d_in[3],  PEMB, 3001 * D_);
    cvt(d_in[4],  QKVW, L_ * 3 * D_ * D_);
    cvt(d_in[5],  QKVB, L_ * 3 * D_);
    cvt(d_in[6],  FCW,  L_ * D_ * D_);
    cvt(d_in[7],  FCB,  L_ * D_);
    cvt(d_in[8],  G1c,  L_ * D_);
    cvt(d_in[9],  B1c,  L_ * D_);
    cvt(d_in[11], C1B,  L_ * DH_);
    cvt(d_in[12], C2W,  L_ * D_ * DH_);
    cvt(d_in[13], C2B,  L_ * D_);
    cvt(d_in[14], G2c,  L_ * D_);
    cvt(d_in[15], B2c,  L_ * D_);
    if (w1L == L_) {
        int n = L_ * DH_ * KCONV;
        w1_reorder2_kernel<<<cdiv(n, 256), 256, 0, stream>>>(
            (const float*)d_in[10], (const u16*)d_in[10], W1R, n, FLAG);
    }

    embed_kernel<<<MROWS, 256, 0, stream>>>(seq, pos, WEMB, PEMB, X, NP);
    zero_pad_kernel<<<cb * 8, 256, 0, stream>>>(Hpad, cb);

    for (int l = 0; l < L_; l++) {
        for (int c = 0; c < nch; c++) {
            const size_t ro = (size_t)c * Mc;
            ln_kernel<<<Mc / 4, 256, 0, stream>>>(
                X + ro * D_, G1c + l * D_, B1c + l * D_, Hpad);
            gemm_mfma<1, 0, 256><<<dim3(6, Mc / 128), 256, 0, stream>>>(
                Hpad, QKVW + (size_t)l * 3 * D_ * D_, QKVB + l * 3 * D_,
                nullptr, nullptr, SCR, Mc, 3 * D_);
            attn_mfma<<<dim3(NH_ * cb, 8), 256, 0, stream>>>(
                SCR, NP + ro, Hpad);
            gemm_mfma<1, 2, 256><<<dim3(2, Mc / 128), 256, 0, stream>>>(
                Hpad, FCW + (size_t)l * D_ * D_, FCB + l * D_,
                X + ro * D_, NP + ro, X + ro * D_, Mc, D_);
        }
        const u16* w1p = W1R + (w1L == L_ ? (size_t)l * DH_ * KCONV : 0);
        if (w1L != L_) {
            int n = DH_ * KCONV;
            w1_reorder2_kernel<<<cdiv(n, 256), 256, 0, stream>>>(
                (const float*)d_in[10] + (size_t)l * DH_ * D_ * 9,
                (const u16*)d_in[10] + (size_t)l * DH_ * D_ * 9,
                W1R, n, FLAG);
        }
        for (int c = 0; c < nch; c++) {
            const size_t ro = (size_t)c * Mc;
            ln_kernel<<<Mc / 4, 256, 0, stream>>>(
                X + ro * D_, G2c + l * D_, B2c + l * D_, Hpad);
            gemm_mfma<2, 1, 2304><<<dim3(8, Mc / 128), 256, 0, stream>>>(
                Hpad, w1p, C1B + l * DH_,
                nullptr, nullptr, SCR, Mc, DH_);
            gemm_mfma<0, 2, 1024><<<dim3(2, Mc / 128), 256, 0, stream>>>(
                SCR, C2W + (size_t)l * D_ * DH_, C2B + l * D_,
                X + ro * D_, NP + ro, X + ro * D_, Mc, D_);
        }
    }

    out_kernel<<<cdiv(out_size, 256), 256, 0, stream>>>(X, NP, d_out, out_size, FLAG);
}

// Round 10
// 1542.852 us; speedup vs baseline: 1.2717x; 1.0941x over previous
//
#include <hip/hip_runtime.h>

// ---------------------------------------------------------------------------
// FastSpeech-style encoder, round 9:
//  - qkv GEMM writes V pre-transposed (Vg[hb][d][t]) straight from registers;
//    QKV buffer is Q|K only (stride 512).
//  - Attention: glds16 staging for K and V^T tiles (XOR-chunk swizzle),
//    B-operand reads shared across the 2 q-sub-tiles, separate Ps buffer ->
//    2 barriers/tile, DS reads ~halved. Was LDS-issue-bound (~8% MfmaUtil).
//  - conv1 GEMM at m97-structure plateau (43% MfmaUtil, 0 conflicts): keep.
// B=32 T=1024 D=256 NH=2 dk=128 D_HID=1024 L=4, conv1 k9p4, conv2 k1.
// ---------------------------------------------------------------------------

#define B_ 32
#define T_ 1024
#define D_ 256
#define NH_ 2
#define DK_ 128
#define DH_ 1024
#define L_ 4
#define MROWS (B_ * T_)        // 32768
#define KCONV (D_ * 9)         // 2304
#define TPAD 1032              // 4 zero + 1024 + 4 zero rows per batch (Hpad)

typedef unsigned short u16;
typedef short bf16x8 __attribute__((ext_vector_type(8)));
typedef float f32x4 __attribute__((ext_vector_type(4)));
typedef u16 u16x8 __attribute__((ext_vector_type(8)));

__device__ __forceinline__ float bf2f(u16 h) {
    union { unsigned int u; float f; } a;
    a.u = ((unsigned int)h) << 16;
    return a.f;
}

__device__ __forceinline__ u16 f2bf(float f) {
    union { float f; unsigned int u; } a;
    a.f = f;
    unsigned int r = a.u + 0x7fffu + ((a.u >> 16) & 1u);  // RNE
    return (u16)(r >> 16);
}

__device__ __forceinline__ void glds16(const u16* g, u16* l) {
    __builtin_amdgcn_global_load_lds(
        (const __attribute__((address_space(1))) void*)g,
        (__attribute__((address_space(3))) void*)l, 16, 0, 0);
}

// --------------------------- dtype detection -------------------------------
__global__ void detect_kernel(const void* wemb_raw, int* flag) {
    __shared__ int cnt;
    if (threadIdx.x == 0) cnt = 0;
    __syncthreads();
    const u16* p = (const u16*)wemb_raw;
    if (p[256 + threadIdx.x] != 0) atomicAdd(&cnt, 1);
    __syncthreads();
    if (threadIdx.x == 0) *flag = (cnt >= 128) ? 1 : 0;   // 1 = bf16, 0 = fp32
}

__global__ void cvt_any_kernel(const void* __restrict__ src, u16* __restrict__ dst,
                               int n, const int* __restrict__ flag) {
    int i = blockIdx.x * 256 + threadIdx.x;
    if (i >= n) return;
    if (*flag) dst[i] = ((const u16*)src)[i];
    else       dst[i] = f2bf(((const float*)src)[i]);
}

// conv1 weights [l][oc][ic=256][kpos=9] -> [l][oc][kpos*256+ic] bf16
__global__ void w1_reorder2_kernel(const float* __restrict__ srcf,
                                   const u16* __restrict__ srch,
                                   u16* __restrict__ out, int n,
                                   const int* __restrict__ flag) {
    int idx = blockIdx.x * 256 + threadIdx.x;
    if (idx >= n) return;
    int l  = idx / (DH_ * KCONV);
    int r  = idx % (DH_ * KCONV);
    int oc = r / KCONV;
    int kk = r % KCONV;
    int kpos = kk >> 8;
    int ic   = kk & 255;
    size_t si = (size_t)l * DH_ * D_ * 9 + (oc * D_ + ic) * 9 + kpos;
    out[idx] = (*flag) ? srch[si] : f2bf(srcf[si]);
}

__global__ void sentinel_kernel(void* out, int out_size) {
    int i = blockIdx.x * 256 + threadIdx.x;
    if (i < out_size) ((u16*)out)[i] = 0x42F6;  // 123.0 bf16 — "ws too small"
}

// --------------------------- small utility kernels -------------------------

__global__ void embed_kernel(const int* __restrict__ seq, const int* __restrict__ pos,
                             const u16* __restrict__ wemb, const u16* __restrict__ pemb,
                             float* __restrict__ X, float* __restrict__ NP) {
    int row = blockIdx.x;
    int d   = threadIdx.x;
    int s = seq[row];
    int p = pos[row];
    X[(size_t)row * D_ + d] = bf2f(wemb[s * D_ + d]) + bf2f(pemb[p * D_ + d]);
    if (d == 0) NP[row] = (s != 0) ? 1.0f : 0.0f;
}

__global__ void zero_pad_kernel(u16* __restrict__ Hp, int nb) {
    int i = blockIdx.x * 256 + threadIdx.x;
    if (i >= nb * 8 * 256) return;
    int b = i / (8 * 256);
    int r = (i / 256) & 7;
    int d = i & 255;
    int row = (r < 4) ? r : (1024 + r);
    Hp[(size_t)(b * TPAD + row) * D_ + d] = 0;
}

// LN: 4 rows/block (1 wave/row); out -> Hpad layout.
__global__ __launch_bounds__(256)
void ln_kernel(const float* __restrict__ x, const u16* __restrict__ g,
               const u16* __restrict__ bta, u16* __restrict__ outp) {
    int wave = threadIdx.x >> 6, lane = threadIdx.x & 63;
    int row = blockIdx.x * 4 + wave;
    const float* xr = x + (size_t)row * D_;
    float4 v = *(const float4*)&xr[lane * 4];
    float s  = v.x + v.y + v.z + v.w;
    float s2 = v.x * v.x + v.y * v.y + v.z * v.z + v.w * v.w;
#pragma unroll
    for (int d = 1; d < 64; d <<= 1) {
        s  += __shfl_xor(s,  d, 64);
        s2 += __shfl_xor(s2, d, 64);
    }
    float m   = s * (1.0f / 256.0f);
    float var = s2 * (1.0f / 256.0f) - m * m;
    float rr  = rsqrtf(var + 1e-5f);
    size_t orow = (size_t)((row >> 10) * TPAD + 4 + (row & 1023)) * D_;
    float vv[4] = {v.x, v.y, v.z, v.w};
#pragma unroll
    for (int k = 0; k < 4; k++) {
        int d = lane * 4 + k;
        outp[orow + d] = f2bf((vv[k] - m) * rr * bf2f(g[d]) + bf2f(bta[d]));
    }
}

__global__ void out_kernel(const float* __restrict__ X, const float* __restrict__ NP,
                           void* __restrict__ out, int out_size,
                           const int* __restrict__ flag) {
    int i = blockIdx.x * 256 + threadIdx.x;
    if (i >= out_size) return;
    const int n1 = MROWS * D_;
    float v = (i < n1) ? X[i] : NP[i - n1];
    if (*flag) ((u16*)out)[i] = f2bf(v);
    else       ((float*)out)[i] = v;
}

// ------------------------------- MFMA GEMM ---------------------------------
// C[M,N] = A[M,K] @ W^T, W: [N][K] bf16 row-major. 128x128 tile, BK=64.
// AMAP: 0 plain A[M][K]; 1 Hpad rows (K=256); 2 Hpad im2col (K=2304).
// EPI:  0 bf16 (+bias); 1 bf16 (+bias, relu); 2 fp32 (+bias, +resid, *mask);
//       3 qkv: n<512 -> bf16 C stride 512; n>=512 -> V transposed into
//       vout[hb][d][t] (hb = (d>>7) + 2*b).
template <int AMAP, int EPI, int K>
__global__ __launch_bounds__(256)
void gemm_mfma(const u16* __restrict__ A, const u16* __restrict__ W,
               const u16* __restrict__ bias, const float* __restrict__ resid,
               const float* __restrict__ mask, void* __restrict__ Cp,
               u16* __restrict__ vout, int M, int N) {
    __shared__ __align__(16) u16 As[128 * 64];
    __shared__ __align__(16) u16 Bs[128 * 64];
    const int tid  = threadIdx.x;
    const int wave = tid >> 6, lane = tid & 63;
    const int quad = lane >> 4, l15 = lane & 15;
    const int m0 = blockIdx.y * 128, n0 = blockIdx.x * 128;
    const int wm = (wave >> 1) * 64, wn = (wave & 1) * 64;
    const int srow = wave * 32;                  // 32 staged rows per wave
    const int row8 = lane >> 3;                  // 0..7 within 8-row group
    const int grp  = ((lane & 7) ^ row8) * 8;    // swizzled col offset (u16)
    f32x4 acc[4][4] = {};

    const u16* pa;
    {
        int m = m0 + srow + row8;
        if (AMAP == 0) pa = A + (size_t)m * K + grp;
        else {
            int hr = (m >> 10) * TPAD + (m & 1023) + (AMAP == 1 ? 4 : 0);
            pa = A + (size_t)hr * D_ + grp;
        }
    }
    const u16* pb = W + (size_t)(n0 + srow + row8) * K + grp;
    constexpr size_t rsA = (AMAP == 0) ? (size_t)K : (size_t)D_;
    constexpr size_t rsB = (size_t)K;

    u16* lda = &As[srow * 64];
    u16* ldb = &Bs[srow * 64];
    const int rg = (quad ^ (l15 & 7)) * 8;       // read col group (u16 offset)

    int kpos = 0;
    constexpr int nkt = K / 64;
    for (int t = 0; t < nkt; t++) {
#pragma unroll
        for (int q = 0; q < 4; q++) {
            glds16(pa + (size_t)q * 8 * rsA, lda + q * 8 * 64);
            glds16(pb + (size_t)q * 8 * rsB, ldb + q * 8 * 64);
        }
        if (AMAP == 2) {
            if (kpos == 8) { kpos = 0; pa += 64 - 8 * 256; pb += 64 - 8 * 256; }
            else           { kpos++;  pa += 256;           pb += 256; }
        } else { pa += 64; pb += 64; }
        __builtin_amdgcn_s_waitcnt(0);
        __syncthreads();
#pragma unroll
        for (int ks = 0; ks < 2; ks++) {
            bf16x8 af[4], bfr[4];
#pragma unroll
            for (int i = 0; i < 4; i++)
                af[i] = *(const bf16x8*)&As[(wm + i * 16 + l15) * 64 + (rg ^ (ks * 32))];
#pragma unroll
            for (int j = 0; j < 4; j++)
                bfr[j] = *(const bf16x8*)&Bs[(wn + j * 16 + l15) * 64 + (rg ^ (ks * 32))];
#pragma unroll
            for (int i = 0; i < 4; i++)
#pragma unroll
                for (int j = 0; j < 4; j++)
                    acc[i][j] = __builtin_amdgcn_mfma_f32_16x16x32_bf16(
                        af[i], bfr[j], acc[i][j], 0, 0, 0);
        }
        __syncthreads();
    }

    float bv[4];
#pragma unroll
    for (int j = 0; j < 4; j++) bv[j] = bf2f(bias[n0 + wn + j * 16 + l15]);
#pragma unroll
    for (int i = 0; i < 4; i++) {
#pragma unroll
        for (int j = 0; j < 4; j++) {
            int n = n0 + wn + j * 16 + l15;
            int mbase = m0 + wm + i * 16 + quad * 4;
            float o[4];
#pragma unroll
            for (int r = 0; r < 4; r++) {
                float v = acc[i][j][r] + bv[j];
                if (EPI == 1) v = fmaxf(v, 0.0f);
                o[r] = v;
            }
            if (EPI == 2) {
#pragma unroll
                for (int r = 0; r < 4; r++) {
                    int m = mbase + r;
                    float v = (o[r] + resid[(size_t)m * N + n]) * mask[m];
                    ((float*)Cp)[(size_t)m * N + n] = v;
                }
            } else if (EPI == 3) {
                if (n0 < 512) {
#pragma unroll
                    for (int r = 0; r < 4; r++)
                        ((u16*)Cp)[(size_t)(mbase + r) * 512 + n] = f2bf(o[r]);
                } else {
                    int dg = n - 512;                    // 0..255
                    int bb = mbase >> 10, tt = mbase & 1023;
                    ushort4 pk;
                    pk.x = f2bf(o[0]); pk.y = f2bf(o[1]);
                    pk.z = f2bf(o[2]); pk.w = f2bf(o[3]);
                    *(ushort4*)&vout[(size_t)((dg >> 7) + (bb << 1)) * (128 * 1024)
                                     + (size_t)(dg & 127) * 1024 + tt] = pk;
                }
            } else {
#pragma unroll
                for (int r = 0; r < 4; r++)
                    ((u16*)Cp)[(size_t)(mbase + r) * N + n] = f2bf(o[r]);
            }
        }
    }
}

// --------------------------- flash MFMA attention --------------------------
// QKV [Mc][512] bf16 (q|k, head h at cols h*128 / 256+h*128).
// Vg [hb][128 d][1024 t] bf16 (pre-transposed V).
// Grid (hb fastest -> XCD locality, qt8 0..7), 256 thr, 128 q/block
// (2 sub-tiles of 16 q per wave). K-tiles of 64 keys, glds16 staging with
// XOR-chunk swizzle, B-frags shared across subs, online softmax, O -> Hpad.
// LDS 54KB: Ks 64x128, Vt 128x64, Ps 4x32x72, npS.
__global__ __launch_bounds__(256, 2)
void attn_mfma(const u16* __restrict__ QKV, const u16* __restrict__ Vg,
               const float* __restrict__ NPg, u16* __restrict__ Hp) {
    __shared__ __align__(16) u16 Ks[64 * 128];
    __shared__ __align__(16) u16 Vt[128 * 64];
    __shared__ __align__(16) u16 Ps[4 * 32 * 72];
    __shared__ float npS[1024];
    const int tid  = threadIdx.x;
    const int wave = tid >> 6, lane = tid & 63;
    const int quad = lane >> 4, l15 = lane & 15;
    const int hb = blockIdx.x;
    const int h = hb & (NH_ - 1), b = hb >> 1;
    const int t0 = blockIdx.y * 128;
    const float scale = 0.08838834764831845f;  // 1/sqrt(128)
    u16* Psw = Ps + wave * 32 * 72;
    const u16* Vgh = Vg + (size_t)hb * (128 * 1024);

    for (int i = tid; i < 1024; i += 256) npS[i] = NPg[b * 1024 + i];

    bf16x8 q_a[2][4];
#pragma unroll
    for (int sub = 0; sub < 2; sub++)
#pragma unroll
        for (int s = 0; s < 4; s++)
            q_a[sub][s] = *(const bf16x8*)(QKV
                + (size_t)(b * 1024 + t0 + sub * 64 + wave * 16 + l15) * 512
                + h * DK_ + s * 32 + quad * 8);

    float m_st[2][4], l_st[2][4];
    f32x4 oacc[2][8] = {};
#pragma unroll
    for (int sub = 0; sub < 2; sub++)
#pragma unroll
        for (int r = 0; r < 4; r++) { m_st[sub][r] = -1e30f; l_st[sub][r] = 0.0f; }

    for (int kk = 0; kk < 16; kk++) {
        const int k0 = kk * 64;
        if (kk) __syncthreads();   // prev tile's Ks/Vt reads complete
        // ---- stage K tile + V^T tile via glds16 (XOR-chunk swizzle) ----
#pragma unroll
        for (int i = 0; i < 4; i++) {
            int c = i * 256 + tid;
            int key = c >> 4, gk = (c & 15) ^ (key & 15);
            glds16(QKV + (size_t)(b * 1024 + k0 + key) * 512 + 256 + h * DK_ + gk * 8,
                   Ks + (size_t)(i * 256 + wave * 64) * 8);
            int d = c >> 3, gv = (c & 7) ^ (d & 7);
            glds16(Vgh + (size_t)d * 1024 + k0 + gv * 8,
                   Vt + (size_t)(i * 256 + wave * 64) * 8);
        }
        __builtin_amdgcn_s_waitcnt(0);
        __syncthreads();

        // ---- S = Q K^T, kb shared across both q-subs ----
        f32x4 s4[2][4] = {};
#pragma unroll
        for (int nt = 0; nt < 4; nt++) {
#pragma unroll
            for (int s = 0; s < 4; s++) {
                bf16x8 kb = *(const bf16x8*)&Ks[(nt * 16 + l15) * 128
                                                + ((s * 4 + quad) ^ l15) * 8];
                s4[0][nt] = __builtin_amdgcn_mfma_f32_16x16x32_bf16(
                    q_a[0][s], kb, s4[0][nt], 0, 0, 0);
                s4[1][nt] = __builtin_amdgcn_mfma_f32_16x16x32_bf16(
                    q_a[1][s], kb, s4[1][nt], 0, 0, 0);
            }
        }

        // ---- mask + online softmax + P->LDS (per sub; Ps is wave-private) --
#pragma unroll
        for (int sub = 0; sub < 2; sub++) {
#pragma unroll
            for (int nt = 0; nt < 4; nt++) {
                bool pad = (npS[k0 + nt * 16 + l15] == 0.0f);
#pragma unroll
                for (int r = 0; r < 4; r++)
                    s4[sub][nt][r] = pad ? -1e30f : s4[sub][nt][r] * scale;
            }
            float alpha[4];
#pragma unroll
            for (int r = 0; r < 4; r++) {
                float v = fmaxf(fmaxf(s4[sub][0][r], s4[sub][1][r]),
                                fmaxf(s4[sub][2][r], s4[sub][3][r]));
#pragma unroll
                for (int d = 1; d < 16; d <<= 1) v = fmaxf(v, __shfl_xor(v, d, 64));
                float mnew = fmaxf(m_st[sub][r], v);
                alpha[r] = __expf(m_st[sub][r] - mnew);
                m_st[sub][r] = mnew;
                l_st[sub][r] *= alpha[r];
            }
#pragma unroll
            for (int nt = 0; nt < 4; nt++)
#pragma unroll
                for (int r = 0; r < 4; r++)
                    s4[sub][nt][r] = __expf(s4[sub][nt][r] - m_st[sub][r]);
#pragma unroll
            for (int r = 0; r < 4; r++) {
                float v = s4[sub][0][r] + s4[sub][1][r] + s4[sub][2][r] + s4[sub][3][r];
#pragma unroll
                for (int d = 1; d < 16; d <<= 1) v += __shfl_xor(v, d, 64);
                l_st[sub][r] += v;
            }
#pragma unroll
            for (int dt = 0; dt < 8; dt++)
#pragma unroll
                for (int r = 0; r < 4; r++) oacc[sub][dt][r] *= alpha[r];
#pragma unroll
            for (int nt = 0; nt < 4; nt++)
#pragma unroll
                for (int r = 0; r < 4; r++)
                    Psw[(sub * 16 + quad * 4 + r) * 72 + nt * 16 + l15] =
                        f2bf(s4[sub][nt][r]);
        }

        // ---- O += P V, vb shared across both q-subs ----
#pragma unroll
        for (int ks = 0; ks < 2; ks++) {
            bf16x8 pa0 = *(const bf16x8*)&Psw[l15 * 72 + ks * 32 + quad * 8];
            bf16x8 pa1 = *(const bf16x8*)&Psw[(16 + l15) * 72 + ks * 32 + quad * 8];
#pragma unroll
            for (int dt = 0; dt < 8; dt++) {
                int d = dt * 16 + l15;
                bf16x8 vb = *(const bf16x8*)&Vt[d * 64
                                                + (((ks * 4 + quad) ^ (d & 7)) * 8)];
                oacc[0][dt] = __builtin_amdgcn_mfma_f32_16x16x32_bf16(
                    pa0, vb, oacc[0][dt], 0, 0, 0);
                oacc[1][dt] = __builtin_amdgcn_mfma_f32_16x16x32_bf16(
                    pa1, vb, oacc[1][dt], 0, 0, 0);
            }
        }
    }

    // ---- epilogue: O / l -> Hpad ----
#pragma unroll
    for (int sub = 0; sub < 2; sub++)
#pragma unroll
        for (int r = 0; r < 4; r++) {
            float inv = 1.0f / l_st[sub][r];
            int t = t0 + sub * 64 + wave * 16 + quad * 4 + r;
            size_t orow = (size_t)(b * TPAD + 4 + t) * D_ + h * DK_;
#pragma unroll
            for (int dt = 0; dt < 8; dt++)
                Hp[orow + dt * 16 + l15] = f2bf(oacc[sub][dt][r] * inv);
        }
}

// ------------------------------- driver ------------------------------------

static inline int cdiv(int a, int b) { return (a + b - 1) / b; }

extern "C" void kernel_launch(void* const* d_in, const int* in_sizes, int n_in,
                              void* d_out, int out_size, void* d_ws, size_t ws_size,
                              hipStream_t stream) {
    const int* seq = (const int*)d_in[0];
    const int* pos = (const int*)d_in[1];
    (void)in_sizes; (void)n_in;

    int   cb = 8, w1L = 1;
    int*   FLAG; float* X; float* NP; u16* Hpad; u16* SCR; u16* W1R;
    u16 *WEMB, *PEMB, *QKVW, *QKVB, *FCW, *FCB, *G1c, *B1c, *C1B, *C2W, *C2B, *G2c, *B2c;

    unsigned char* wsb = (unsigned char*)d_ws;
    size_t off;
    auto build = [&](int cb_, int w1L_) -> size_t {
        off = 0;
        auto take = [&](size_t bytes) {
            unsigned char* p = wsb + off;
            off += (bytes + 255) & ~(size_t)255;
            return p;
        };
        FLAG = (int*)  take(4);
        X    = (float*)take((size_t)MROWS * D_ * 4);
        NP   = (float*)take((size_t)MROWS * 4);
        Hpad = (u16*)  take((size_t)cb_ * TPAD * D_ * 2);
        SCR  = (u16*)  take((size_t)cb_ * T_ * DH_ * 2);
        W1R  = (u16*)  take((size_t)w1L_ * DH_ * KCONV * 2);
        WEMB = (u16*)  take((size_t)300 * D_ * 2);
        PEMB = (u16*)  take((size_t)3001 * D_ * 2);
        QKVW = (u16*)  take((size_t)L_ * 3 * D_ * D_ * 2);
        QKVB = (u16*)  take((size_t)L_ * 3 * D_ * 2);
        FCW  = (u16*)  take((size_t)L_ * D_ * D_ * 2);
        FCB  = (u16*)  take((size_t)L_ * D_ * 2);
        G1c  = (u16*)  take((size_t)L_ * D_ * 2);
        B1c  = (u16*)  take((size_t)L_ * D_ * 2);
        C1B  = (u16*)  take((size_t)L_ * DH_ * 2);
        C2W  = (u16*)  take((size_t)L_ * D_ * DH_ * 2);
        C2B  = (u16*)  take((size_t)L_ * D_ * 2);
        G2c  = (u16*)  take((size_t)L_ * D_ * 2);
        B2c  = (u16*)  take((size_t)L_ * D_ * 2);
        return off;
    };
    if      (build(32, L_) <= ws_size) { cb = 32; w1L = L_; }
    else if (build(8,  L_) <= ws_size) { cb = 8;  w1L = L_; }
    else if (build(8,  1)  <= ws_size) { cb = 8;  w1L = 1;  }
    else {
        sentinel_kernel<<<cdiv(out_size, 256), 256, 0, stream>>>(d_out, out_size);
        return;
    }
    const int nch = B_ / cb;
    const int Mc  = cb * T_;

    detect_kernel<<<1, 256, 0, stream>>>(d_in[2], FLAG);
    auto cvt = [&](const void* src, u16* dst, int n) {
        cvt_any_kernel<<<cdiv(n, 256), 256, 0, stream>>>(src, dst, n, FLAG);
    };
    cvt(d_in[2],  WEMB, 300 * D_);
    cvt(d_in[3],  PEMB, 3001 * D_);
    cvt(d_in[4],  QKVW, L_ * 3 * D_ * D_);
    cvt(d_in[5],  QKVB, L_ * 3 * D_);
    cvt(d_in[6],  FCW,  L_ * D_ * D_);
    cvt(d_in[7],  FCB,  L_ * D_);
    cvt(d_in[8],  G1c,  L_ * D_);
    cvt(d_in[9],  B1c,  L_ * D_);
    cvt(d_in[11], C1B,  L_ * DH_);
    cvt(d_in[12], C2W,  L_ * D_ * DH_);
    cvt(d_in[13], C2B,  L_ * D_);
    cvt(d_in[14], G2c,  L_ * D_);
    cvt(d_in[15], B2c,  L_ * D_);
    if (w1L == L_) {
        int n = L_ * DH_ * KCONV;
        w1_reorder2_kernel<<<cdiv(n, 256), 256, 0, stream>>>(
            (const float*)d_in[10], (const u16*)d_in[10], W1R, n, FLAG);
    }

    embed_kernel<<<MROWS, 256, 0, stream>>>(seq, pos, WEMB, PEMB, X, NP);
    zero_pad_kernel<<<cb * 8, 256, 0, stream>>>(Hpad, cb);

    for (int l = 0; l < L_; l++) {
        for (int c = 0; c < nch; c++) {
            const size_t ro = (size_t)c * Mc;
            u16* QKV = SCR;                              // [Mc][512] q|k
            u16* Vg  = SCR + (size_t)Mc * 512;           // [NH*cb][128][1024]
            ln_kernel<<<Mc / 4, 256, 0, stream>>>(
                X + ro * D_, G1c + l * D_, B1c + l * D_, Hpad);
            gemm_mfma<1, 3, 256><<<dim3(6, Mc / 128), 256, 0, stream>>>(
                Hpad, QKVW + (size_t)l * 3 * D_ * D_, QKVB + l * 3 * D_,
                nullptr, nullptr, QKV, Vg, Mc, 768);
            attn_mfma<<<dim3(NH_ * cb, 8), 256, 0, stream>>>(
                QKV, Vg, NP + ro, Hpad);
            gemm_mfma<1, 2, 256><<<dim3(2, Mc / 128), 256, 0, stream>>>(
                Hpad, FCW + (size_t)l * D_ * D_, FCB + l * D_,
                X + ro * D_, NP + ro, X + ro * D_, nullptr, Mc, D_);
        }
        const u16* w1p = W1R + (w1L == L_ ? (size_t)l * DH_ * KCONV : 0);
        if (w1L != L_) {
            int n = DH_ * KCONV;
            w1_reorder2_kernel<<<cdiv(n, 256), 256, 0, stream>>>(
                (const float*)d_in[10] + (size_t)l * DH_ * D_ * 9,
                (const u16*)d_in[10] + (size_t)l * DH_ * D_ * 9,
                W1R, n, FLAG);
        }
        for (int c = 0; c < nch; c++) {
            const size_t ro = (size_t)c * Mc;
            ln_kernel<<<Mc / 4, 256, 0, stream>>>(
                X + ro * D_, G2c + l * D_, B2c + l * D_, Hpad);
            gemm_mfma<2, 1, 2304><<<dim3(8, Mc / 128), 256, 0, stream>>>(
                Hpad, w1p, C1B + l * DH_,
                nullptr, nullptr, SCR, nullptr, Mc, DH_);
            gemm_mfma<0, 2, 1024><<<dim3(2, Mc / 128), 256, 0, stream>>>(
                SCR, C2W + (size_t)l * D_ * DH_, C2B + l * D_,
                X + ro * D_, NP + ro, X + ro * D_, nullptr, Mc, D_);
        }
    }

    out_kernel<<<cdiv(out_size, 256), 256, 0, stream>>>(X, NP, d_out, out_size, FLAG);
}